// Round 8
// baseline (350.426 us; speedup 1.0000x reference)
//
#include <hip/hip_runtime.h>
#include <hip/hip_fp16.h>
#include <math.h>

// Problem constants (match reference file)
constexpr int DG  = 128;
constexpr int DIN = 128;
constexpr int DH  = 64;
constexpr int DFC = 32;
constexpr int DC  = 10;
constexpr int CAP    = 80;    // adjacency capacity/node (deg ~ Poisson(32); P(>80)~1e-13)
constexpr int NB     = 2048;  // dst buckets for the sort-based build
constexpr int ABLK   = 256;   // edge-chunk blocks (hist/binplace use identical partition)
constexpr int SCAP   = 2048;  // staging capacity per bucket (avg fill ~1568)
constexpr int MAXNPB = 52;    // max nodes per bucket supported by k_rows LDS

// ---------------- build 1: per-block LDS histogram of both endpoints ----------------
__global__ __launch_bounds__(256) void k_hist(const int* __restrict__ src,
                                              const int* __restrict__ dst,
                                              int* __restrict__ hist,
                                              int E, int EPB, int NPB) {
    __shared__ int h[NB];
    for (int i = threadIdx.x; i < NB; i += 256) h[i] = 0;
    __syncthreads();
    int e0 = blockIdx.x * EPB, e1 = min(e0 + EPB, E);
    for (int i = e0 + threadIdx.x; i < e1; i += 256) {
        int u = src[i], v = dst[i];
        atomicAdd(&h[v / NPB], 1);
        atomicAdd(&h[u / NPB], 1);
    }
    __syncthreads();
    int* o = hist + (size_t)blockIdx.x * NB;
    for (int i = threadIdx.x; i < NB; i += 256) o[i] = h[i];
}

// ---------------- build 2: per-(block,bucket) staging bases + bucket totals ----------------
// also zeroes the pooling accumulators (folds two memset dispatches)
__global__ __launch_bounds__(256) void k_expand(const int* __restrict__ hist,
                                                int* __restrict__ base,
                                                int* __restrict__ ecnt,
                                                float* __restrict__ sums,
                                                int* __restrict__ cnts) {
    int b = blockIdx.x * 256 + threadIdx.x;   // 0..NB-1 (grid = NB/256)
    int run = b * SCAP;
    for (int blk = 0; blk < ABLK; blk++) {
        base[(size_t)blk * NB + b] = run;
        run += hist[(size_t)blk * NB + b];
    }
    ecnt[b] = min(run - b * SCAP, SCAP);
    for (int i = b; i < DG * DH; i += NB) sums[i] = 0.0f;
    if (b < DG) cnts[b] = 0;
}

// ---------------- build 3: place packed entries into bucket-grouped staging ----------------
__global__ __launch_bounds__(256) void k_binplace(const int* __restrict__ src,
                                                  const int* __restrict__ dst,
                                                  const int* __restrict__ base,
                                                  int* __restrict__ staging,
                                                  int E, int EPB, int NPB) {
    __shared__ int lcnt[NB];
    __shared__ int lbase[NB];
    int blk = blockIdx.x;
    for (int i = threadIdx.x; i < NB; i += 256) {
        lcnt[i]  = 0;
        lbase[i] = base[(size_t)blk * NB + i];
    }
    __syncthreads();
    int e0 = blk * EPB, e1 = min(e0 + EPB, E);
    for (int i = e0 + threadIdx.x; i < e1; i += 256) {
        int u = src[i], v = dst[i];
        int bv = v / NPB, bu = u / NPB;
        int rv = atomicAdd(&lcnt[bv], 1);
        int sv = lbase[bv] + rv;
        if (sv < (bv + 1) * SCAP) staging[sv] = ((v - bv * NPB) << 17) | u;
        int ru = atomicAdd(&lcnt[bu], 1);
        int su = lbase[bu] + ru;
        if (su < (bu + 1) * SCAP) staging[su] = ((u - bu * NPB) << 17) | v;
    }
}

// ---------------- build 4: one block per bucket -> adj rows + cnt + dinv ----------------
__global__ __launch_bounds__(256) void k_rows(const int* __restrict__ staging,
                                              const int* __restrict__ ecnt,
                                              int* __restrict__ adj,
                                              int* __restrict__ cnt,
                                              float* __restrict__ dinv,
                                              int N, int NPB) {
    __shared__ int rows[MAXNPB * CAP];   // 16.6 KB
    __shared__ int cur[MAXNPB];
    int b = blockIdx.x;
    int nbase = b * NPB;
    int nn = min(NPB, N - nbase);
    if (nn <= 0) return;
    for (int i = threadIdx.x; i < nn; i += 256) cur[i] = 0;
    __syncthreads();
    int s0 = b * SCAP, s1 = s0 + ecnt[b];
    for (int i = s0 + threadIdx.x; i < s1; i += 256) {
        int e  = staging[i];
        int vl = e >> 17;
        int u  = e & 0x1FFFF;
        int p  = atomicAdd(&cur[vl], 1);
        if (p < CAP) rows[vl * CAP + p] = u;
    }
    __syncthreads();
    for (int s = threadIdx.x; s < nn * CAP; s += 256) {
        int node = s / CAP, p = s - node * CAP;
        if (p < min(cur[node], CAP))
            adj[(size_t)(nbase + node) * CAP + p] = rows[s];
    }
    for (int i = threadIdx.x; i < nn; i += 256) {
        int c = cur[i];
        cnt[nbase + i]  = c;
        dinv[nbase + i] = rsqrtf(1.0f + (float)c);
    }
}

// ---------------- input linear: out = f16(relu(x @ W + b)) ----------------
__global__ __launch_bounds__(256) void k_lin_in(const float* __restrict__ x,
                                                const float* __restrict__ W,
                                                const float* __restrict__ b,
                                                __half* __restrict__ out, int n) {
    __shared__ float sx[16 * DIN];        // 8 KB staged rows
    __shared__ float part[16 * 4 * DH];   // 16 KB partials
    int t = threadIdx.x;
    int lane = t & 63, w = t >> 6;
    float wreg[32];
#pragma unroll
    for (int i = 0; i < 32; i++) wreg[i] = W[(w * 32 + i) * DH + lane];
    float bb = b[lane];
    int tile = blockIdx.x * 16;
    const float4* xsrc = (const float4*)(x + (size_t)tile * DIN);
    float4* sx4 = (float4*)sx;
    sx4[t]       = xsrc[t];
    sx4[t + 256] = xsrc[t + 256];
    __syncthreads();
#pragma unroll 1
    for (int r = 0; r < 16; r++) {
        const float4* xr = (const float4*)(sx + r * DIN + w * 32);
        float a0 = 0.f, a1 = 0.f, a2 = 0.f, a3 = 0.f;
#pragma unroll
        for (int q = 0; q < 8; q++) {
            float4 xv = xr[q];
            a0 = fmaf(xv.x, wreg[q * 4 + 0], a0);
            a1 = fmaf(xv.y, wreg[q * 4 + 1], a1);
            a2 = fmaf(xv.z, wreg[q * 4 + 2], a2);
            a3 = fmaf(xv.w, wreg[q * 4 + 3], a3);
        }
        part[(r * 4 + w) * DH + lane] = (a0 + a1) + (a2 + a3);
    }
    __syncthreads();
#pragma unroll
    for (int q = 0; q < 4; q++) {
        int r = w * 4 + q;
        float s = part[(r * 4 + 0) * DH + lane] + part[(r * 4 + 1) * DH + lane]
                + part[(r * 4 + 2) * DH + lane] + part[(r * 4 + 3) * DH + lane] + bb;
        out[(size_t)(tile + r) * DH + lane] = __float2half(fmaxf(s, 0.0f));
    }
}

// ---------------- 64x64 matmul (f16 in, f16 out, *dinv): full W in 64 regs ----------------
__global__ __launch_bounds__(256) void k_mm64(const __half* __restrict__ h,
                                              const float* __restrict__ W,
                                              const float* __restrict__ dinv,
                                              __half* __restrict__ out, int n) {
    __shared__ float sx[16 * DH];
    int t = threadIdx.x, lane = t & 63, w = t >> 6;
    float wreg[64];
#pragma unroll
    for (int i = 0; i < 64; i++) wreg[i] = W[i * DH + lane];
    int tile = blockIdx.x * 16;
    {
        const __half2* hsrc = (const __half2*)(h + (size_t)tile * DH);
        float2* sx2 = (float2*)sx;
        sx2[t * 2]     = __half22float2(hsrc[t * 2]);
        sx2[t * 2 + 1] = __half22float2(hsrc[t * 2 + 1]);
    }
    __syncthreads();
#pragma unroll
    for (int q = 0; q < 4; q++) {
        int r = w * 4 + q;
        const float4* xr = (const float4*)(sx + r * DH);
        float a0 = 0.f, a1 = 0.f, a2 = 0.f, a3 = 0.f;
#pragma unroll
        for (int p = 0; p < 16; p++) {
            float4 xv = xr[p];
            a0 = fmaf(xv.x, wreg[p * 4 + 0], a0);
            a1 = fmaf(xv.y, wreg[p * 4 + 1], a1);
            a2 = fmaf(xv.z, wreg[p * 4 + 2], a2);
            a3 = fmaf(xv.w, wreg[p * 4 + 3], a3);
        }
        float dv = dinv[tile + r];
        out[(size_t)(tile + r) * DH + lane] = __float2half(((a0 + a1) + (a2 + a3)) * dv);
    }
}

// ---------------- chunked gather: no inner shuffles, b128 row loads ----------------
// lane = (g,c): g = neighbor slot 0..7, c = 16B chunk 0..7 of the 128B f16 row.
// One b128 load instruction covers 8 neighbor rows; reduce over g at the end.
__global__ __launch_bounds__(256) void k_gather(const int* __restrict__ cnt,
                                                const int* __restrict__ adj,
                                                const float4* __restrict__ xws4,
                                                const float* __restrict__ dinv,
                                                const float* __restrict__ b,
                                                __half* __restrict__ out, int n) {
    int lane = threadIdx.x & 63;
    int v    = blockIdx.x * 4 + (threadIdx.x >> 6);
    if (v >= n) return;
    int g = lane >> 3;   // neighbor slot
    int c = lane & 7;    // feature chunk
    int len = min(cnt[v], CAP);
    const int* row = adj + (size_t)v * CAP;
    float a0 = 0.f, a1 = 0.f, a2 = 0.f, a3 = 0.f;
    float a4 = 0.f, a5 = 0.f, a6 = 0.f, a7 = 0.f;
    int it_n = (len + 7) >> 3;
#pragma unroll 2
    for (int it = 0; it < it_n; it++) {
        int pos = it * 8 + g;   // < 80 always: in-bounds of row
        int u = row[pos];
        if (pos < len) {
            float4 ch = xws4[(size_t)u * 8 + c];
            const __half2* h2 = (const __half2*)&ch;
            float2 p0 = __half22float2(h2[0]);
            float2 p1 = __half22float2(h2[1]);
            float2 p2 = __half22float2(h2[2]);
            float2 p3 = __half22float2(h2[3]);
            a0 += p0.x; a1 += p0.y; a2 += p1.x; a3 += p1.y;
            a4 += p2.x; a5 += p2.y; a6 += p3.x; a7 += p3.y;
        }
    }
    // reduce over the 8 neighbor slots (lanes with same c, stride 8)
#pragma unroll
    for (int o = 8; o < 64; o <<= 1) {
        a0 += __shfl_xor(a0, o); a1 += __shfl_xor(a1, o);
        a2 += __shfl_xor(a2, o); a3 += __shfl_xor(a3, o);
        a4 += __shfl_xor(a4, o); a5 += __shfl_xor(a5, o);
        a6 += __shfl_xor(a6, o); a7 += __shfl_xor(a7, o);
    }
    if (g == 0) {
        float4 sv = xws4[(size_t)v * 8 + c];   // self row chunk
        const __half2* s2 = (const __half2*)&sv;
        float2 s0 = __half22float2(s2[0]);
        float2 s1 = __half22float2(s2[1]);
        float2 s2f = __half22float2(s2[2]);
        float2 s3 = __half22float2(s2[3]);
        float dv = dinv[v];
        float4 b0 = ((const float4*)b)[c * 2];
        float4 b1 = ((const float4*)b)[c * 2 + 1];
        __half2 o[4];
        o[0] = __floats2half2_rn(fmaxf(dv * (a0 + s0.x) + b0.x, 0.0f),
                                 fmaxf(dv * (a1 + s0.y) + b0.y, 0.0f));
        o[1] = __floats2half2_rn(fmaxf(dv * (a2 + s1.x) + b0.z, 0.0f),
                                 fmaxf(dv * (a3 + s1.y) + b0.w, 0.0f));
        o[2] = __floats2half2_rn(fmaxf(dv * (a4 + s2f.x) + b1.x, 0.0f),
                                 fmaxf(dv * (a5 + s2f.y) + b1.y, 0.0f));
        o[3] = __floats2half2_rn(fmaxf(dv * (a6 + s3.x) + b1.z, 0.0f),
                                 fmaxf(dv * (a7 + s3.y) + b1.w, 0.0f));
        ((float4*)out)[(size_t)v * 8 + c] = *(const float4*)o;
    }
}

// ---------------- pooling (run-length accumulate over sorted batch, f16 in) ----------------
__global__ __launch_bounds__(256) void k_pool(const __half* __restrict__ h,
                                              const int* __restrict__ batch,
                                              float* __restrict__ sums,
                                              int* __restrict__ cnts, int n) {
    int lane = threadIdx.x & 63;
    int w    = blockIdx.x * 4 + (threadIdx.x >> 6);
    int start = w * 64;
    if (start >= n) return;
    int end  = min(start + 64, n);
    int curg = batch[start];
    float acc = 0.f;
    int   c   = 0;
    for (int node = start; node < end; node++) {
        int g = batch[node];
        if (g != curg) {
            atomicAdd(&sums[curg * DH + lane], acc);
            if (lane == 0) atomicAdd(&cnts[curg], c);
            acc = 0.f; c = 0; curg = g;
        }
        acc += __half2float(h[(size_t)node * DH + lane]);
        c++;
    }
    atomicAdd(&sums[curg * DH + lane], acc);
    if (lane == 0) atomicAdd(&cnts[curg], c);
}

// ---------------- head: mean, fc1+relu, fc2, log_softmax ----------------
__global__ __launch_bounds__(64) void k_head(const float* __restrict__ sums,
                                             const int* __restrict__ cnts,
                                             const float* __restrict__ Wf1,
                                             const float* __restrict__ bf1,
                                             const float* __restrict__ Wf2,
                                             const float* __restrict__ bf2,
                                             float* __restrict__ out) {
    int g = blockIdx.x, lane = threadIdx.x;
    float cnt    = (float)max(cnts[g], 1);
    float pooled = sums[g * DH + lane] / cnt;
    float acc = (lane < DFC) ? bf1[lane] : 0.f;
    for (int k = 0; k < DH; k++) {
        float pk = __shfl(pooled, k);
        if (lane < DFC) acc = fmaf(pk, Wf1[k * DFC + lane], acc);
    }
    float gv = fmaxf(acc, 0.f);
    float acc2 = (lane < DC) ? bf2[lane] : 0.f;
    for (int k = 0; k < DFC; k++) {
        float gk = __shfl(gv, k);
        if (lane < DC) acc2 = fmaf(gk, Wf2[k * DC + lane], acc2);
    }
    float v = (lane < DC) ? acc2 : -INFINITY;
    float m = v;
    for (int o = 8; o; o >>= 1) m = fmaxf(m, __shfl_xor(m, o));
    float e = (lane < DC) ? expf(v - m) : 0.f;
    float s = e;
    for (int o = 8; o; o >>= 1) s += __shfl_xor(s, o);
    if (lane < DC) out[g * DC + lane] = v - m - logf(s);
}

extern "C" void kernel_launch(void* const* d_in, const int* in_sizes, int n_in,
                              void* d_out, int out_size, void* d_ws, size_t ws_size,
                              hipStream_t stream) {
    const float* x    = (const float*)d_in[0];
    const int*   ei   = (const int*)d_in[1];
    const int*   batch= (const int*)d_in[2];
    const float* W_in = (const float*)d_in[3];
    const float* b_in = (const float*)d_in[4];
    const float* W1   = (const float*)d_in[5];
    const float* b1   = (const float*)d_in[6];
    const float* W2   = (const float*)d_in[7];
    const float* b2   = (const float*)d_in[8];
    const float* Wf1  = (const float*)d_in[9];
    const float* bf1  = (const float*)d_in[10];
    const float* Wf2  = (const float*)d_in[11];
    const float* bf2  = (const float*)d_in[12];
    float* out = (float*)d_out;

    const int E = in_sizes[1] / 2;      // 1,600,000
    const int N = in_sizes[0] / DIN;    // 100,000
    const int* src = ei;
    const int* dst = ei + E;

    const int NPB = (N + NB - 1) / NB;          // nodes per bucket (49)
    const int NBU = (N + NPB - 1) / NPB;        // buckets used (2041)
    const int EPB = (E + ABLK - 1) / ABLK;      // edges per hist/binplace block

    char* ws = (char*)d_ws;
    size_t off = 0;
    auto alloc = [&](size_t bytes) -> void* {
        void* p = ws + off;
        off = (off + bytes + 255) & ~(size_t)255;
        return p;
    };
    int*    cnt     = (int*)   alloc((size_t)N * 4);
    float*  dinv    = (float*) alloc((size_t)N * 4);
    int*    adj     = (int*)   alloc((size_t)N * CAP * 4);      // 32 MB
    int*    hist    = (int*)   alloc((size_t)ABLK * NB * 4);    // 2 MB
    int*    base    = (int*)   alloc((size_t)ABLK * NB * 4);    // 2 MB
    int*    ecnt    = (int*)   alloc((size_t)NB * 4);
    int*    staging = (int*)   alloc((size_t)NB * SCAP * 4);    // 16.8 MB
    __half* hA      = (__half*)alloc((size_t)N * DH * 2);       // 12.8 MB
    __half* hX      = (__half*)alloc((size_t)N * DH * 2);       // 12.8 MB
    float*  sums    = (float*) alloc((size_t)DG * DH * 4);
    int*    cnts    = (int*)   alloc((size_t)DG * 4);

    // atomic-free adjacency build: hist -> bases(+pool zero) -> binplace -> rows(+cnt+dinv)
    k_hist<<<ABLK, 256, 0, stream>>>(src, dst, hist, E, EPB, NPB);
    k_expand<<<NB / 256, 256, 0, stream>>>(hist, base, ecnt, sums, cnts);
    k_binplace<<<ABLK, 256, 0, stream>>>(src, dst, base, staging, E, EPB, NPB);
    k_rows<<<NBU, 256, 0, stream>>>(staging, ecnt, adj, cnt, dinv, N, NPB);

    // input linear + relu (f16 out)
    k_lin_in<<<N / 16, 256, 0, stream>>>(x, W_in, b_in, hA, N);

    // conv1: xws = f16((h@W1)*dinv); gather + self + bias + relu
    k_mm64<<<N / 16, 256, 0, stream>>>(hA, W1, dinv, hX, N);
    k_gather<<<(N + 3) / 4, 256, 0, stream>>>(cnt, adj, (const float4*)hX, dinv, b1, hA, N);

    // conv2
    k_mm64<<<N / 16, 256, 0, stream>>>(hA, W2, dinv, hX, N);
    k_gather<<<(N + 3) / 4, 256, 0, stream>>>(cnt, adj, (const float4*)hX, dinv, b2, hA, N);

    // pooling
    int pw = (N + 63) / 64;
    k_pool<<<(pw + 3) / 4, 256, 0, stream>>>(hA, batch, sums, cnts, N);

    // head
    k_head<<<DG, 64, 0, stream>>>(sums, cnts, Wf1, bf1, Wf2, bf2, out);
}

// Round 9
// 319.306 us; speedup vs baseline: 1.0975x; 1.0975x over previous
//
#include <hip/hip_runtime.h>
#include <hip/hip_fp16.h>
#include <math.h>

// Problem constants (match reference file)
constexpr int DG  = 128;
constexpr int DIN = 128;
constexpr int DH  = 64;
constexpr int DFC = 32;
constexpr int DC  = 10;
constexpr int CAP    = 80;    // adjacency capacity/node (deg ~ Poisson(32); P(>80)~1e-13)
constexpr int NB     = 2048;  // dst buckets for the sort-based build
constexpr int ABLK   = 256;   // edge-chunk blocks (hist/binplace use identical partition)
constexpr int SCAP   = 2048;  // staging capacity per bucket (avg fill ~1568)
constexpr int MAXNPB = 52;    // max nodes per bucket supported by k_rows LDS

// ---------------- build 1: per-block LDS histogram, bucket-major output ----------------
__global__ __launch_bounds__(256) void k_hist(const int* __restrict__ src,
                                              const int* __restrict__ dst,
                                              int* __restrict__ histT,   // [NB][ABLK]
                                              int E, int EPB, int NPB) {
    __shared__ int h[NB];
    for (int i = threadIdx.x; i < NB; i += 256) h[i] = 0;
    __syncthreads();
    int e0 = blockIdx.x * EPB, e1 = min(e0 + EPB, E);
    for (int i = e0 + threadIdx.x; i < e1; i += 256) {
        int u = src[i], v = dst[i];
        atomicAdd(&h[v / NPB], 1);
        atomicAdd(&h[u / NPB], 1);
    }
    __syncthreads();
    for (int i = threadIdx.x; i < NB; i += 256)
        histT[(size_t)i * ABLK + blockIdx.x] = h[i];
}

// ---------------- build 2: per-bucket LDS scan -> bases + totals (+pool zero) ----------------
__global__ __launch_bounds__(256) void k_expand(const int* __restrict__ histT,
                                                int* __restrict__ baseT,   // [NB][ABLK]
                                                int* __restrict__ ecnt,
                                                float* __restrict__ sums,
                                                int* __restrict__ cnts) {
    __shared__ int s[256];
    int b = blockIdx.x, t = threadIdx.x;
    int v = histT[(size_t)b * ABLK + t];
    s[t] = v;
    __syncthreads();
    for (int o = 1; o < 256; o <<= 1) {
        int tv = (t >= o) ? s[t - o] : 0;
        __syncthreads();
        s[t] += tv;
        __syncthreads();
    }
    int incl = s[t];
    baseT[(size_t)b * ABLK + t] = b * SCAP + incl - v;   // exclusive + bucket offset
    if (t == 255) ecnt[b] = min(incl, SCAP);
    int gid = b * 256 + t;
    if (gid < DG * DH) sums[gid] = 0.0f;
    if (gid < DG) cnts[gid] = 0;
}

// ---------------- build 3: place packed entries into bucket-grouped staging ----------------
__global__ __launch_bounds__(256) void k_binplace(const int* __restrict__ src,
                                                  const int* __restrict__ dst,
                                                  const int* __restrict__ baseT,
                                                  int* __restrict__ staging,
                                                  int E, int EPB, int NPB) {
    __shared__ int lcnt[NB];
    __shared__ int lbase[NB];
    int blk = blockIdx.x;
    for (int i = threadIdx.x; i < NB; i += 256) {
        lcnt[i]  = 0;
        lbase[i] = baseT[(size_t)i * ABLK + blk];
    }
    __syncthreads();
    int e0 = blk * EPB, e1 = min(e0 + EPB, E);
    for (int i = e0 + threadIdx.x; i < e1; i += 256) {
        int u = src[i], v = dst[i];
        int bv = v / NPB, bu = u / NPB;
        int rv = atomicAdd(&lcnt[bv], 1);
        int sv = lbase[bv] + rv;
        if (sv < (bv + 1) * SCAP) staging[sv] = ((v - bv * NPB) << 17) | u;
        int ru = atomicAdd(&lcnt[bu], 1);
        int su = lbase[bu] + ru;
        if (su < (bu + 1) * SCAP) staging[su] = ((u - bu * NPB) << 17) | v;
    }
}

// ---------------- build 4: one block per bucket -> adj rows + cnt + dinv ----------------
__global__ __launch_bounds__(256) void k_rows(const int* __restrict__ staging,
                                              const int* __restrict__ ecnt,
                                              int* __restrict__ adj,
                                              int* __restrict__ cnt,
                                              float* __restrict__ dinv,
                                              int N, int NPB) {
    __shared__ int rows[MAXNPB * CAP];   // 16.6 KB
    __shared__ int cur[MAXNPB];
    int b = blockIdx.x;
    int nbase = b * NPB;
    int nn = min(NPB, N - nbase);
    if (nn <= 0) return;
    for (int i = threadIdx.x; i < nn; i += 256) cur[i] = 0;
    __syncthreads();
    int s0 = b * SCAP, s1 = s0 + ecnt[b];
    for (int i = s0 + threadIdx.x; i < s1; i += 256) {
        int e  = staging[i];
        int vl = e >> 17;
        int u  = e & 0x1FFFF;
        int p  = atomicAdd(&cur[vl], 1);
        if (p < CAP) rows[vl * CAP + p] = u;
    }
    __syncthreads();
    for (int s = threadIdx.x; s < nn * CAP; s += 256) {
        int node = s / CAP, p = s - node * CAP;
        if (p < min(cur[node], CAP))
            adj[(size_t)(nbase + node) * CAP + p] = rows[s];
    }
    for (int i = threadIdx.x; i < nn; i += 256) {
        int c = cur[i];
        cnt[nbase + i]  = c;
        dinv[nbase + i] = rsqrtf(1.0f + (float)c);
    }
}

// ---------------- input linear: out = f16(relu(x @ W + b)) ----------------
__global__ __launch_bounds__(256) void k_lin_in(const float* __restrict__ x,
                                                const float* __restrict__ W,
                                                const float* __restrict__ b,
                                                __half* __restrict__ out, int n) {
    __shared__ float sx[16 * DIN];        // 8 KB staged rows
    __shared__ float part[16 * 4 * DH];   // 16 KB partials
    int t = threadIdx.x;
    int lane = t & 63, w = t >> 6;
    float wreg[32];
#pragma unroll
    for (int i = 0; i < 32; i++) wreg[i] = W[(w * 32 + i) * DH + lane];
    float bb = b[lane];
    int tile = blockIdx.x * 16;
    const float4* xsrc = (const float4*)(x + (size_t)tile * DIN);
    float4* sx4 = (float4*)sx;
    sx4[t]       = xsrc[t];
    sx4[t + 256] = xsrc[t + 256];
    __syncthreads();
#pragma unroll 1
    for (int r = 0; r < 16; r++) {
        const float4* xr = (const float4*)(sx + r * DIN + w * 32);
        float a0 = 0.f, a1 = 0.f, a2 = 0.f, a3 = 0.f;
#pragma unroll
        for (int q = 0; q < 8; q++) {
            float4 xv = xr[q];
            a0 = fmaf(xv.x, wreg[q * 4 + 0], a0);
            a1 = fmaf(xv.y, wreg[q * 4 + 1], a1);
            a2 = fmaf(xv.z, wreg[q * 4 + 2], a2);
            a3 = fmaf(xv.w, wreg[q * 4 + 3], a3);
        }
        part[(r * 4 + w) * DH + lane] = (a0 + a1) + (a2 + a3);
    }
    __syncthreads();
#pragma unroll
    for (int q = 0; q < 4; q++) {
        int r = w * 4 + q;
        float s = part[(r * 4 + 0) * DH + lane] + part[(r * 4 + 1) * DH + lane]
                + part[(r * 4 + 2) * DH + lane] + part[(r * 4 + 3) * DH + lane] + bb;
        out[(size_t)(tile + r) * DH + lane] = __float2half(fmaxf(s, 0.0f));
    }
}

// ---------------- 64x64 matmul (f16 in, f16 out, *dinv): full W in 64 regs ----------------
__global__ __launch_bounds__(256) void k_mm64(const __half* __restrict__ h,
                                              const float* __restrict__ W,
                                              const float* __restrict__ dinv,
                                              __half* __restrict__ out, int n) {
    __shared__ float sx[16 * DH];
    int t = threadIdx.x, lane = t & 63, w = t >> 6;
    float wreg[64];
#pragma unroll
    for (int i = 0; i < 64; i++) wreg[i] = W[i * DH + lane];
    int tile = blockIdx.x * 16;
    {
        const __half2* hsrc = (const __half2*)(h + (size_t)tile * DH);
        float2* sx2 = (float2*)sx;
        sx2[t * 2]     = __half22float2(hsrc[t * 2]);
        sx2[t * 2 + 1] = __half22float2(hsrc[t * 2 + 1]);
    }
    __syncthreads();
#pragma unroll
    for (int q = 0; q < 4; q++) {
        int r = w * 4 + q;
        const float4* xr = (const float4*)(sx + r * DH);
        float a0 = 0.f, a1 = 0.f, a2 = 0.f, a3 = 0.f;
#pragma unroll
        for (int p = 0; p < 16; p++) {
            float4 xv = xr[p];
            a0 = fmaf(xv.x, wreg[p * 4 + 0], a0);
            a1 = fmaf(xv.y, wreg[p * 4 + 1], a1);
            a2 = fmaf(xv.z, wreg[p * 4 + 2], a2);
            a3 = fmaf(xv.w, wreg[p * 4 + 3], a3);
        }
        float dv = dinv[tile + r];
        out[(size_t)(tile + r) * DH + lane] = __float2half(((a0 + a1) + (a2 + a3)) * dv);
    }
}

// ---------------- fixed-stride gather, MLP-widened (round-6 proven form) ----------------
// Lane-parallel index preload (row[lane]) -> shfl broadcast -> 4 independent
// row-gathers in flight per half-wave (8 per wave). Only dependence: shfl->load.
__global__ __launch_bounds__(256) void k_gather(const int* __restrict__ cnt,
                                                const int* __restrict__ adj,
                                                const __half2* __restrict__ xws,
                                                const float* __restrict__ dinv,
                                                const float* __restrict__ b,
                                                __half* __restrict__ out, int n) {
    int lane = threadIdx.x & 63;
    int v    = blockIdx.x * 4 + (threadIdx.x >> 6);
    if (v >= n) return;
    int half_id = lane >> 5, fp = lane & 31;
    int len = min(cnt[v], CAP);
    const int* row = adj + (size_t)v * CAP;
    int idx = 0;
    if (lane < len) idx = row[lane];
    int len64 = min(len, 64);
    float ax0 = 0.f, ay0 = 0.f, ax1 = 0.f, ay1 = 0.f;
    float ax2 = 0.f, ay2 = 0.f, ax3 = 0.f, ay3 = 0.f;
    int k = half_id;
    for (; k + 6 < len64; k += 8) {
        int u0 = __shfl(idx, k);
        int u1 = __shfl(idx, k + 2);
        int u2 = __shfl(idx, k + 4);
        int u3 = __shfl(idx, k + 6);
        float2 f0 = __half22float2(xws[(size_t)u0 * 32 + fp]);
        float2 f1 = __half22float2(xws[(size_t)u1 * 32 + fp]);
        float2 f2 = __half22float2(xws[(size_t)u2 * 32 + fp]);
        float2 f3 = __half22float2(xws[(size_t)u3 * 32 + fp]);
        ax0 += f0.x; ay0 += f0.y; ax1 += f1.x; ay1 += f1.y;
        ax2 += f2.x; ay2 += f2.y; ax3 += f3.x; ay3 += f3.y;
    }
    for (; k < len64; k += 2) {
        int u0 = __shfl(idx, k);
        float2 f0 = __half22float2(xws[(size_t)u0 * 32 + fp]);
        ax0 += f0.x; ay0 += f0.y;
    }
    for (int j = 64 + half_id; j < len; j += 2) {  // rare tail (deg > 64)
        float2 f0 = __half22float2(xws[(size_t)row[j] * 32 + fp]);
        ax0 += f0.x; ay0 += f0.y;
    }
    float ax = (ax0 + ax1) + (ax2 + ax3);
    float ay = (ay0 + ay1) + (ay2 + ay3);
    ax += __shfl_xor(ax, 32);
    ay += __shfl_xor(ay, 32);
    if (half_id == 0) {
        float2 s  = __half22float2(xws[(size_t)v * 32 + fp]);
        float  dv = dinv[v];
        float2 bb = ((const float2*)b)[fp];
        __half2 o = __floats2half2_rn(fmaxf(dv * (ax + s.x) + bb.x, 0.0f),
                                      fmaxf(dv * (ay + s.y) + bb.y, 0.0f));
        ((__half2*)out)[(size_t)v * 32 + fp] = o;
    }
}

// ---------------- pooling (run-length accumulate over sorted batch, f16 in) ----------------
__global__ __launch_bounds__(256) void k_pool(const __half* __restrict__ h,
                                              const int* __restrict__ batch,
                                              float* __restrict__ sums,
                                              int* __restrict__ cnts, int n) {
    int lane = threadIdx.x & 63;
    int w    = blockIdx.x * 4 + (threadIdx.x >> 6);
    int start = w * 64;
    if (start >= n) return;
    int end  = min(start + 64, n);
    int curg = batch[start];
    float acc = 0.f;
    int   c   = 0;
    for (int node = start; node < end; node++) {
        int g = batch[node];
        if (g != curg) {
            atomicAdd(&sums[curg * DH + lane], acc);
            if (lane == 0) atomicAdd(&cnts[curg], c);
            acc = 0.f; c = 0; curg = g;
        }
        acc += __half2float(h[(size_t)node * DH + lane]);
        c++;
    }
    atomicAdd(&sums[curg * DH + lane], acc);
    if (lane == 0) atomicAdd(&cnts[curg], c);
}

// ---------------- head: mean, fc1+relu, fc2, log_softmax ----------------
__global__ __launch_bounds__(64) void k_head(const float* __restrict__ sums,
                                             const int* __restrict__ cnts,
                                             const float* __restrict__ Wf1,
                                             const float* __restrict__ bf1,
                                             const float* __restrict__ Wf2,
                                             const float* __restrict__ bf2,
                                             float* __restrict__ out) {
    int g = blockIdx.x, lane = threadIdx.x;
    float cnt    = (float)max(cnts[g], 1);
    float pooled = sums[g * DH + lane] / cnt;
    float acc = (lane < DFC) ? bf1[lane] : 0.f;
    for (int k = 0; k < DH; k++) {
        float pk = __shfl(pooled, k);
        if (lane < DFC) acc = fmaf(pk, Wf1[k * DFC + lane], acc);
    }
    float gv = fmaxf(acc, 0.f);
    float acc2 = (lane < DC) ? bf2[lane] : 0.f;
    for (int k = 0; k < DFC; k++) {
        float gk = __shfl(gv, k);
        if (lane < DC) acc2 = fmaf(gk, Wf2[k * DC + lane], acc2);
    }
    float v = (lane < DC) ? acc2 : -INFINITY;
    float m = v;
    for (int o = 8; o; o >>= 1) m = fmaxf(m, __shfl_xor(m, o));
    float e = (lane < DC) ? expf(v - m) : 0.f;
    float s = e;
    for (int o = 8; o; o >>= 1) s += __shfl_xor(s, o);
    if (lane < DC) out[g * DC + lane] = v - m - logf(s);
}

extern "C" void kernel_launch(void* const* d_in, const int* in_sizes, int n_in,
                              void* d_out, int out_size, void* d_ws, size_t ws_size,
                              hipStream_t stream) {
    const float* x    = (const float*)d_in[0];
    const int*   ei   = (const int*)d_in[1];
    const int*   batch= (const int*)d_in[2];
    const float* W_in = (const float*)d_in[3];
    const float* b_in = (const float*)d_in[4];
    const float* W1   = (const float*)d_in[5];
    const float* b1   = (const float*)d_in[6];
    const float* W2   = (const float*)d_in[7];
    const float* b2   = (const float*)d_in[8];
    const float* Wf1  = (const float*)d_in[9];
    const float* bf1  = (const float*)d_in[10];
    const float* Wf2  = (const float*)d_in[11];
    const float* bf2  = (const float*)d_in[12];
    float* out = (float*)d_out;

    const int E = in_sizes[1] / 2;      // 1,600,000
    const int N = in_sizes[0] / DIN;    // 100,000
    const int* src = ei;
    const int* dst = ei + E;

    const int NPB = (N + NB - 1) / NB;          // nodes per bucket (49)
    const int NBU = (N + NPB - 1) / NPB;        // buckets used (2041)
    const int EPB = (E + ABLK - 1) / ABLK;      // edges per hist/binplace block

    char* ws = (char*)d_ws;
    size_t off = 0;
    auto alloc = [&](size_t bytes) -> void* {
        void* p = ws + off;
        off = (off + bytes + 255) & ~(size_t)255;
        return p;
    };
    int*    cnt     = (int*)   alloc((size_t)N * 4);
    float*  dinv    = (float*) alloc((size_t)N * 4);
    int*    adj     = (int*)   alloc((size_t)N * CAP * 4);      // 32 MB
    int*    histT   = (int*)   alloc((size_t)ABLK * NB * 4);    // 2 MB
    int*    baseT   = (int*)   alloc((size_t)ABLK * NB * 4);    // 2 MB
    int*    ecnt    = (int*)   alloc((size_t)NB * 4);
    int*    staging = (int*)   alloc((size_t)NB * SCAP * 4);    // 16.8 MB
    __half* hA      = (__half*)alloc((size_t)N * DH * 2);       // 12.8 MB
    __half* hX      = (__half*)alloc((size_t)N * DH * 2);       // 12.8 MB
    float*  sums    = (float*) alloc((size_t)DG * DH * 4);
    int*    cnts    = (int*)   alloc((size_t)DG * 4);

    // atomic-free adjacency build: hist(T) -> per-bucket scan(+pool zero) -> binplace -> rows
    k_hist<<<ABLK, 256, 0, stream>>>(src, dst, histT, E, EPB, NPB);
    k_expand<<<NB, 256, 0, stream>>>(histT, baseT, ecnt, sums, cnts);
    k_binplace<<<ABLK, 256, 0, stream>>>(src, dst, baseT, staging, E, EPB, NPB);
    k_rows<<<NBU, 256, 0, stream>>>(staging, ecnt, adj, cnt, dinv, N, NPB);

    // input linear + relu (f16 out)
    k_lin_in<<<N / 16, 256, 0, stream>>>(x, W_in, b_in, hA, N);

    // conv1: xws = f16((h@W1)*dinv); gather + self + bias + relu
    k_mm64<<<N / 16, 256, 0, stream>>>(hA, W1, dinv, hX, N);
    k_gather<<<(N + 3) / 4, 256, 0, stream>>>(cnt, adj, (const __half2*)hX, dinv, b1, hA, N);

    // conv2
    k_mm64<<<N / 16, 256, 0, stream>>>(hA, W2, dinv, hX, N);
    k_gather<<<(N + 3) / 4, 256, 0, stream>>>(cnt, adj, (const __half2*)hX, dinv, b2, hA, N);

    // pooling
    int pw = (N + 63) / 64;
    k_pool<<<(pw + 3) / 4, 256, 0, stream>>>(hA, batch, sums, cnts, N);

    // head
    k_head<<<DG, 64, 0, stream>>>(sums, cnts, Wf1, bf1, Wf2, bf2, out);
}

// Round 10
// 318.547 us; speedup vs baseline: 1.1001x; 1.0024x over previous
//
#include <hip/hip_runtime.h>
#include <hip/hip_fp16.h>
#include <math.h>

// Problem constants (match reference file)
constexpr int DG  = 128;
constexpr int DIN = 128;
constexpr int DH  = 64;
constexpr int DFC = 32;
constexpr int DC  = 10;
constexpr int CAP    = 80;    // adjacency capacity/node (deg ~ Poisson(32); P(>80)~1e-13)
constexpr int NB     = 2048;  // dst buckets for the sort-based build
constexpr int ABLK   = 256;   // edge-chunk blocks (hist/binplace use identical partition)
constexpr int SCAP   = 2048;  // staging capacity per bucket (avg fill ~1568)
constexpr int MAXNPB = 52;    // max nodes per bucket supported by k_rows LDS

// ---------------- build 1: per-block LDS histogram, bucket-major output ----------------
__global__ __launch_bounds__(256) void k_hist(const int* __restrict__ src,
                                              const int* __restrict__ dst,
                                              int* __restrict__ histT,   // [NB][ABLK]
                                              int E, int EPB, int NPB) {
    __shared__ int h[NB];
    for (int i = threadIdx.x; i < NB; i += 256) h[i] = 0;
    __syncthreads();
    int e0 = blockIdx.x * EPB, e1 = min(e0 + EPB, E);
    for (int i = e0 + threadIdx.x; i < e1; i += 256) {
        int u = src[i], v = dst[i];
        atomicAdd(&h[v / NPB], 1);
        atomicAdd(&h[u / NPB], 1);
    }
    __syncthreads();
    for (int i = threadIdx.x; i < NB; i += 256)
        histT[(size_t)i * ABLK + blockIdx.x] = h[i];
}

// ---------------- build 2: per-bucket LDS scan -> bases + totals (+pool zero) ----------------
__global__ __launch_bounds__(256) void k_expand(const int* __restrict__ histT,
                                                int* __restrict__ baseT,   // [NB][ABLK]
                                                int* __restrict__ ecnt,
                                                float* __restrict__ sums,
                                                int* __restrict__ cnts) {
    __shared__ int s[256];
    int b = blockIdx.x, t = threadIdx.x;
    int v = histT[(size_t)b * ABLK + t];
    s[t] = v;
    __syncthreads();
    for (int o = 1; o < 256; o <<= 1) {
        int tv = (t >= o) ? s[t - o] : 0;
        __syncthreads();
        s[t] += tv;
        __syncthreads();
    }
    int incl = s[t];
    baseT[(size_t)b * ABLK + t] = b * SCAP + incl - v;   // exclusive + bucket offset
    if (t == 255) ecnt[b] = min(incl, SCAP);
    int gid = b * 256 + t;
    if (gid < DG * DH) sums[gid] = 0.0f;
    if (gid < DG) cnts[gid] = 0;
}

// ---------------- build 3: place packed entries into bucket-grouped staging ----------------
__global__ __launch_bounds__(256) void k_binplace(const int* __restrict__ src,
                                                  const int* __restrict__ dst,
                                                  const int* __restrict__ baseT,
                                                  int* __restrict__ staging,
                                                  int E, int EPB, int NPB) {
    __shared__ int lcnt[NB];
    __shared__ int lbase[NB];
    int blk = blockIdx.x;
    for (int i = threadIdx.x; i < NB; i += 256) {
        lcnt[i]  = 0;
        lbase[i] = baseT[(size_t)i * ABLK + blk];
    }
    __syncthreads();
    int e0 = blk * EPB, e1 = min(e0 + EPB, E);
    for (int i = e0 + threadIdx.x; i < e1; i += 256) {
        int u = src[i], v = dst[i];
        int bv = v / NPB, bu = u / NPB;
        int rv = atomicAdd(&lcnt[bv], 1);
        int sv = lbase[bv] + rv;
        if (sv < (bv + 1) * SCAP) staging[sv] = ((v - bv * NPB) << 17) | u;
        int ru = atomicAdd(&lcnt[bu], 1);
        int su = lbase[bu] + ru;
        if (su < (bu + 1) * SCAP) staging[su] = ((u - bu * NPB) << 17) | v;
    }
}

// ---------------- build 4: one block per bucket -> adj rows + cnt + dinv ----------------
__global__ __launch_bounds__(256) void k_rows(const int* __restrict__ staging,
                                              const int* __restrict__ ecnt,
                                              int* __restrict__ adj,
                                              int* __restrict__ cnt,
                                              float* __restrict__ dinv,
                                              int N, int NPB) {
    __shared__ int rows[MAXNPB * CAP];   // 16.6 KB
    __shared__ int cur[MAXNPB];
    int b = blockIdx.x;
    int nbase = b * NPB;
    int nn = min(NPB, N - nbase);
    if (nn <= 0) return;
    for (int i = threadIdx.x; i < nn; i += 256) cur[i] = 0;
    __syncthreads();
    int s0 = b * SCAP, s1 = s0 + ecnt[b];
    for (int i = s0 + threadIdx.x; i < s1; i += 256) {
        int e  = staging[i];
        int vl = e >> 17;
        int u  = e & 0x1FFFF;
        int p  = atomicAdd(&cur[vl], 1);
        if (p < CAP) rows[vl * CAP + p] = u;
    }
    __syncthreads();
    for (int s = threadIdx.x; s < nn * CAP; s += 256) {
        int node = s / CAP, p = s - node * CAP;
        if (p < min(cur[node], CAP))
            adj[(size_t)(nbase + node) * CAP + p] = rows[s];
    }
    for (int i = threadIdx.x; i < nn; i += 256) {
        int c = cur[i];
        cnt[nbase + i]  = c;
        dinv[nbase + i] = rsqrtf(1.0f + (float)c);
    }
}

// ---------------- fused input linear + conv1 matmul ----------------
// phase A: h = relu(x @ Wi + bi) kept in LDS; phase B: out = f16((h @ W1) * dinv)
__global__ __launch_bounds__(256) void k_lin2(const float* __restrict__ x,
                                              const float* __restrict__ Wi,
                                              const float* __restrict__ bi,
                                              const float* __restrict__ W1,
                                              const float* __restrict__ dinv,
                                              __half* __restrict__ out, int n) {
    __shared__ float sx[16 * DIN];        // 8 KB staged rows
    __shared__ float part[16 * 4 * DH];   // 16 KB partials
    __shared__ float sh[16 * DH];         // 4 KB h tile
    int t = threadIdx.x;
    int lane = t & 63, w = t >> 6;
    float wreg[32];
#pragma unroll
    for (int i = 0; i < 32; i++) wreg[i] = Wi[(w * 32 + i) * DH + lane];
    float bb = bi[lane];
    int tile = blockIdx.x * 16;
    const float4* xsrc = (const float4*)(x + (size_t)tile * DIN);
    float4* sx4 = (float4*)sx;
    sx4[t]       = xsrc[t];
    sx4[t + 256] = xsrc[t + 256];
    __syncthreads();
#pragma unroll 1
    for (int r = 0; r < 16; r++) {
        const float4* xr = (const float4*)(sx + r * DIN + w * 32);
        float a0 = 0.f, a1 = 0.f, a2 = 0.f, a3 = 0.f;
#pragma unroll
        for (int q = 0; q < 8; q++) {
            float4 xv = xr[q];
            a0 = fmaf(xv.x, wreg[q * 4 + 0], a0);
            a1 = fmaf(xv.y, wreg[q * 4 + 1], a1);
            a2 = fmaf(xv.z, wreg[q * 4 + 2], a2);
            a3 = fmaf(xv.w, wreg[q * 4 + 3], a3);
        }
        part[(r * 4 + w) * DH + lane] = (a0 + a1) + (a2 + a3);
    }
    __syncthreads();
#pragma unroll
    for (int q = 0; q < 4; q++) {
        int r = w * 4 + q;
        float s = part[(r * 4 + 0) * DH + lane] + part[(r * 4 + 1) * DH + lane]
                + part[(r * 4 + 2) * DH + lane] + part[(r * 4 + 3) * DH + lane] + bb;
        sh[r * DH + lane] = fmaxf(s, 0.0f);
    }
    // phase B: W1 into regs, h tile already in LDS
    float w1[64];
#pragma unroll
    for (int i = 0; i < 64; i++) w1[i] = W1[i * DH + lane];
    __syncthreads();
#pragma unroll
    for (int q = 0; q < 4; q++) {
        int r = w * 4 + q;
        const float4* hr = (const float4*)(sh + r * DH);
        float a0 = 0.f, a1 = 0.f, a2 = 0.f, a3 = 0.f;
#pragma unroll
        for (int p = 0; p < 16; p++) {
            float4 xv = hr[p];
            a0 = fmaf(xv.x, w1[p * 4 + 0], a0);
            a1 = fmaf(xv.y, w1[p * 4 + 1], a1);
            a2 = fmaf(xv.z, w1[p * 4 + 2], a2);
            a3 = fmaf(xv.w, w1[p * 4 + 3], a3);
        }
        float dv = dinv[tile + r];
        out[(size_t)(tile + r) * DH + lane] = __float2half(((a0 + a1) + (a2 + a3)) * dv);
    }
}

// ---------------- 64x64 matmul (f16 in, f16 out, *dinv): full W in 64 regs ----------------
__global__ __launch_bounds__(256) void k_mm64(const __half* __restrict__ h,
                                              const float* __restrict__ W,
                                              const float* __restrict__ dinv,
                                              __half* __restrict__ out, int n) {
    __shared__ float sx[16 * DH];
    int t = threadIdx.x, lane = t & 63, w = t >> 6;
    float wreg[64];
#pragma unroll
    for (int i = 0; i < 64; i++) wreg[i] = W[i * DH + lane];
    int tile = blockIdx.x * 16;
    {
        const __half2* hsrc = (const __half2*)(h + (size_t)tile * DH);
        float2* sx2 = (float2*)sx;
        sx2[t * 2]     = __half22float2(hsrc[t * 2]);
        sx2[t * 2 + 1] = __half22float2(hsrc[t * 2 + 1]);
    }
    __syncthreads();
#pragma unroll
    for (int q = 0; q < 4; q++) {
        int r = w * 4 + q;
        const float4* xr = (const float4*)(sx + r * DH);
        float a0 = 0.f, a1 = 0.f, a2 = 0.f, a3 = 0.f;
#pragma unroll
        for (int p = 0; p < 16; p++) {
            float4 xv = xr[p];
            a0 = fmaf(xv.x, wreg[p * 4 + 0], a0);
            a1 = fmaf(xv.y, wreg[p * 4 + 1], a1);
            a2 = fmaf(xv.z, wreg[p * 4 + 2], a2);
            a3 = fmaf(xv.w, wreg[p * 4 + 3], a3);
        }
        float dv = dinv[tile + r];
        out[(size_t)(tile + r) * DH + lane] = __float2half(((a0 + a1) + (a2 + a3)) * dv);
    }
}

// ---------------- gather: shfl-broadcast indices, pk_add_f16 pairing, 32-bit addr ----------------
__global__ __launch_bounds__(256) void k_gather(const int* __restrict__ cnt,
                                                const int* __restrict__ adj,
                                                const __half2* __restrict__ xws,
                                                const float* __restrict__ dinv,
                                                const float* __restrict__ b,
                                                __half* __restrict__ out, int n) {
    int lane = threadIdx.x & 63;
    int v    = blockIdx.x * 4 + (threadIdx.x >> 6);
    if (v >= n) return;
    int half_id = lane >> 5, fp = lane & 31;
    int len = min(cnt[v], CAP);
    const int* row = adj + (size_t)v * CAP;
    int idx = 0;
    if (lane < len) idx = row[lane];
    int len64 = min(len, 64);
    const char* xb = (const char*)xws;
    int fpo = fp << 2;
    float ax = 0.f, ay = 0.f;
    int k = half_id;
    // chunks of 16 neighbors (8 per half-wave); pk-pair then flush to f32
    for (; k + 14 < len64; k += 16) {
        int u0 = __shfl(idx, k);
        int u1 = __shfl(idx, k + 2);
        int u2 = __shfl(idx, k + 4);
        int u3 = __shfl(idx, k + 6);
        int u4 = __shfl(idx, k + 8);
        int u5 = __shfl(idx, k + 10);
        int u6 = __shfl(idx, k + 12);
        int u7 = __shfl(idx, k + 14);
        __half2 h0 = *(const __half2*)(xb + ((u0 << 7) | fpo));
        __half2 h1 = *(const __half2*)(xb + ((u1 << 7) | fpo));
        __half2 h2 = *(const __half2*)(xb + ((u2 << 7) | fpo));
        __half2 h3 = *(const __half2*)(xb + ((u3 << 7) | fpo));
        h0 = __hadd2(h0, *(const __half2*)(xb + ((u4 << 7) | fpo)));
        h1 = __hadd2(h1, *(const __half2*)(xb + ((u5 << 7) | fpo)));
        h2 = __hadd2(h2, *(const __half2*)(xb + ((u6 << 7) | fpo)));
        h3 = __hadd2(h3, *(const __half2*)(xb + ((u7 << 7) | fpo)));
        float2 f0 = __half22float2(h0);
        float2 f1 = __half22float2(h1);
        float2 f2 = __half22float2(h2);
        float2 f3 = __half22float2(h3);
        ax += (f0.x + f1.x) + (f2.x + f3.x);
        ay += (f0.y + f1.y) + (f2.y + f3.y);
    }
    for (; k < len64; k += 2) {
        int u0 = __shfl(idx, k);
        float2 f0 = __half22float2(*(const __half2*)(xb + ((u0 << 7) | fpo)));
        ax += f0.x; ay += f0.y;
    }
    for (int j = 64 + half_id; j < len; j += 2) {  // rare tail (deg > 64)
        float2 f0 = __half22float2(xws[(size_t)row[j] * 32 + fp]);
        ax += f0.x; ay += f0.y;
    }
    ax += __shfl_xor(ax, 32);
    ay += __shfl_xor(ay, 32);
    if (half_id == 0) {
        float2 s  = __half22float2(xws[(size_t)v * 32 + fp]);
        float  dv = dinv[v];
        float2 bb = ((const float2*)b)[fp];
        __half2 o = __floats2half2_rn(fmaxf(dv * (ax + s.x) + bb.x, 0.0f),
                                      fmaxf(dv * (ay + s.y) + bb.y, 0.0f));
        ((__half2*)out)[(size_t)v * 32 + fp] = o;
    }
}

// ---------------- pooling (run-length accumulate over sorted batch, f16 in) ----------------
__global__ __launch_bounds__(256) void k_pool(const __half* __restrict__ h,
                                              const int* __restrict__ batch,
                                              float* __restrict__ sums,
                                              int* __restrict__ cnts, int n) {
    int lane = threadIdx.x & 63;
    int w    = blockIdx.x * 4 + (threadIdx.x >> 6);
    int start = w * 64;
    if (start >= n) return;
    int end  = min(start + 64, n);
    int curg = batch[start];
    float acc = 0.f;
    int   c   = 0;
    for (int node = start; node < end; node++) {
        int g = batch[node];
        if (g != curg) {
            atomicAdd(&sums[curg * DH + lane], acc);
            if (lane == 0) atomicAdd(&cnts[curg], c);
            acc = 0.f; c = 0; curg = g;
        }
        acc += __half2float(h[(size_t)node * DH + lane]);
        c++;
    }
    atomicAdd(&sums[curg * DH + lane], acc);
    if (lane == 0) atomicAdd(&cnts[curg], c);
}

// ---------------- head: mean, fc1+relu, fc2, log_softmax ----------------
__global__ __launch_bounds__(64) void k_head(const float* __restrict__ sums,
                                             const int* __restrict__ cnts,
                                             const float* __restrict__ Wf1,
                                             const float* __restrict__ bf1,
                                             const float* __restrict__ Wf2,
                                             const float* __restrict__ bf2,
                                             float* __restrict__ out) {
    int g = blockIdx.x, lane = threadIdx.x;
    float cnt    = (float)max(cnts[g], 1);
    float pooled = sums[g * DH + lane] / cnt;
    float acc = (lane < DFC) ? bf1[lane] : 0.f;
    for (int k = 0; k < DH; k++) {
        float pk = __shfl(pooled, k);
        if (lane < DFC) acc = fmaf(pk, Wf1[k * DFC + lane], acc);
    }
    float gv = fmaxf(acc, 0.f);
    float acc2 = (lane < DC) ? bf2[lane] : 0.f;
    for (int k = 0; k < DFC; k++) {
        float gk = __shfl(gv, k);
        if (lane < DC) acc2 = fmaf(gk, Wf2[k * DC + lane], acc2);
    }
    float v = (lane < DC) ? acc2 : -INFINITY;
    float m = v;
    for (int o = 8; o; o >>= 1) m = fmaxf(m, __shfl_xor(m, o));
    float e = (lane < DC) ? expf(v - m) : 0.f;
    float s = e;
    for (int o = 8; o; o >>= 1) s += __shfl_xor(s, o);
    if (lane < DC) out[g * DC + lane] = v - m - logf(s);
}

extern "C" void kernel_launch(void* const* d_in, const int* in_sizes, int n_in,
                              void* d_out, int out_size, void* d_ws, size_t ws_size,
                              hipStream_t stream) {
    const float* x    = (const float*)d_in[0];
    const int*   ei   = (const int*)d_in[1];
    const int*   batch= (const int*)d_in[2];
    const float* W_in = (const float*)d_in[3];
    const float* b_in = (const float*)d_in[4];
    const float* W1   = (const float*)d_in[5];
    const float* b1   = (const float*)d_in[6];
    const float* W2   = (const float*)d_in[7];
    const float* b2   = (const float*)d_in[8];
    const float* Wf1  = (const float*)d_in[9];
    const float* bf1  = (const float*)d_in[10];
    const float* Wf2  = (const float*)d_in[11];
    const float* bf2  = (const float*)d_in[12];
    float* out = (float*)d_out;

    const int E = in_sizes[1] / 2;      // 1,600,000
    const int N = in_sizes[0] / DIN;    // 100,000
    const int* src = ei;
    const int* dst = ei + E;

    const int NPB = (N + NB - 1) / NB;          // nodes per bucket (49)
    const int NBU = (N + NPB - 1) / NPB;        // buckets used (2041)
    const int EPB = (E + ABLK - 1) / ABLK;      // edges per hist/binplace block

    char* ws = (char*)d_ws;
    size_t off = 0;
    auto alloc = [&](size_t bytes) -> void* {
        void* p = ws + off;
        off = (off + bytes + 255) & ~(size_t)255;
        return p;
    };
    int*    cnt     = (int*)   alloc((size_t)N * 4);
    float*  dinv    = (float*) alloc((size_t)N * 4);
    int*    adj     = (int*)   alloc((size_t)N * CAP * 4);      // 32 MB
    int*    histT   = (int*)   alloc((size_t)ABLK * NB * 4);    // 2 MB
    int*    baseT   = (int*)   alloc((size_t)ABLK * NB * 4);    // 2 MB
    int*    ecnt    = (int*)   alloc((size_t)NB * 4);
    int*    staging = (int*)   alloc((size_t)NB * SCAP * 4);    // 16.8 MB
    __half* hA      = (__half*)alloc((size_t)N * DH * 2);       // 12.8 MB
    __half* hX      = (__half*)alloc((size_t)N * DH * 2);       // 12.8 MB
    float*  sums    = (float*) alloc((size_t)DG * DH * 4);
    int*    cnts    = (int*)   alloc((size_t)DG * 4);

    // atomic-free adjacency build: hist(T) -> per-bucket scan(+pool zero) -> binplace -> rows
    k_hist<<<ABLK, 256, 0, stream>>>(src, dst, histT, E, EPB, NPB);
    k_expand<<<NB, 256, 0, stream>>>(histT, baseT, ecnt, sums, cnts);
    k_binplace<<<ABLK, 256, 0, stream>>>(src, dst, baseT, staging, E, EPB, NPB);
    k_rows<<<NBU, 256, 0, stream>>>(staging, ecnt, adj, cnt, dinv, N, NPB);

    // fused: h0 = relu(xWi+bi); xws1 = f16((h0@W1)*dinv)
    k_lin2<<<N / 16, 256, 0, stream>>>(x, W_in, b_in, W1, dinv, hX, N);

    // conv1 gather + self + bias + relu
    k_gather<<<(N + 3) / 4, 256, 0, stream>>>(cnt, adj, (const __half2*)hX, dinv, b1, hA, N);

    // conv2
    k_mm64<<<N / 16, 256, 0, stream>>>(hA, W2, dinv, hX, N);
    k_gather<<<(N + 3) / 4, 256, 0, stream>>>(cnt, adj, (const __half2*)hX, dinv, b2, hA, N);

    // pooling
    int pw = (N + 63) / 64;
    k_pool<<<(pw + 3) / 4, 256, 0, stream>>>(hA, batch, sums, cnts, N);

    // head
    k_head<<<DG, 64, 0, stream>>>(sums, cnts, Wf1, bf1, Wf2, bf2, out);
}

// Round 11
// 289.887 us; speedup vs baseline: 1.2088x; 1.0989x over previous
//
#include <hip/hip_runtime.h>
#include <hip/hip_fp16.h>
#include <math.h>

// Problem constants (match reference file)
constexpr int DG  = 128;
constexpr int DIN = 128;
constexpr int DH  = 64;
constexpr int DFC = 32;
constexpr int DC  = 10;
constexpr int CAP    = 80;    // adjacency capacity/node (deg ~ Poisson(32); P(>80)~1e-13)
constexpr int NB     = 2048;  // dst buckets for the sort-based build
constexpr int ABLK   = 256;   // edge-chunk blocks (hist/binplace use identical partition)
constexpr int SCAP   = 2048;  // staging capacity per bucket (avg fill ~1568)
constexpr int MAXNPB = 52;    // max nodes per bucket supported by k_rows LDS

typedef _Float16 f16;
typedef f16  f16x8 __attribute__((ext_vector_type(8)));
typedef float f32x4 __attribute__((ext_vector_type(4)));

// XOR-swizzled byte offset within a 128-B LDS row (bank-conflict-free frag reads)
__device__ __forceinline__ int swz(int row, int byte_in_row) {
    return row * 128 + (byte_in_row ^ ((row & 7) << 4));
}

// ---------------- build 1: per-block LDS histogram, bucket-major output ----------------
__global__ __launch_bounds__(256) void k_hist(const int* __restrict__ src,
                                              const int* __restrict__ dst,
                                              int* __restrict__ histT,   // [NB][ABLK]
                                              int E, int EPB, int NPB) {
    __shared__ int h[NB];
    for (int i = threadIdx.x; i < NB; i += 256) h[i] = 0;
    __syncthreads();
    int e0 = blockIdx.x * EPB, e1 = min(e0 + EPB, E);
    for (int i = e0 + threadIdx.x; i < e1; i += 256) {
        int u = src[i], v = dst[i];
        atomicAdd(&h[v / NPB], 1);
        atomicAdd(&h[u / NPB], 1);
    }
    __syncthreads();
    for (int i = threadIdx.x; i < NB; i += 256)
        histT[(size_t)i * ABLK + blockIdx.x] = h[i];
}

// ---------------- build 2: per-bucket LDS scan -> bases + totals (+pool zero) ----------------
__global__ __launch_bounds__(256) void k_expand(const int* __restrict__ histT,
                                                int* __restrict__ baseT,   // [NB][ABLK]
                                                int* __restrict__ ecnt,
                                                float* __restrict__ sums,
                                                int* __restrict__ cnts) {
    __shared__ int s[256];
    int b = blockIdx.x, t = threadIdx.x;
    int v = histT[(size_t)b * ABLK + t];
    s[t] = v;
    __syncthreads();
    for (int o = 1; o < 256; o <<= 1) {
        int tv = (t >= o) ? s[t - o] : 0;
        __syncthreads();
        s[t] += tv;
        __syncthreads();
    }
    int incl = s[t];
    baseT[(size_t)b * ABLK + t] = b * SCAP + incl - v;   // exclusive + bucket offset
    if (t == 255) ecnt[b] = min(incl, SCAP);
    int gid = b * 256 + t;
    if (gid < DG * DH) sums[gid] = 0.0f;
    if (gid < DG) cnts[gid] = 0;
}

// ---------------- build 3: place packed entries into bucket-grouped staging ----------------
__global__ __launch_bounds__(256) void k_binplace(const int* __restrict__ src,
                                                  const int* __restrict__ dst,
                                                  const int* __restrict__ baseT,
                                                  int* __restrict__ staging,
                                                  int E, int EPB, int NPB) {
    __shared__ int lcnt[NB];
    __shared__ int lbase[NB];
    int blk = blockIdx.x;
    for (int i = threadIdx.x; i < NB; i += 256) {
        lcnt[i]  = 0;
        lbase[i] = baseT[(size_t)i * ABLK + blk];
    }
    __syncthreads();
    int e0 = blk * EPB, e1 = min(e0 + EPB, E);
    for (int i = e0 + threadIdx.x; i < e1; i += 256) {
        int u = src[i], v = dst[i];
        int bv = v / NPB, bu = u / NPB;
        int rv = atomicAdd(&lcnt[bv], 1);
        int sv = lbase[bv] + rv;
        if (sv < (bv + 1) * SCAP) staging[sv] = ((v - bv * NPB) << 17) | u;
        int ru = atomicAdd(&lcnt[bu], 1);
        int su = lbase[bu] + ru;
        if (su < (bu + 1) * SCAP) staging[su] = ((u - bu * NPB) << 17) | v;
    }
}

// ---------------- build 4: one block per bucket -> adj rows + cnt + dinv ----------------
__global__ __launch_bounds__(256) void k_rows(const int* __restrict__ staging,
                                              const int* __restrict__ ecnt,
                                              int* __restrict__ adj,
                                              int* __restrict__ cnt,
                                              float* __restrict__ dinv,
                                              int N, int NPB) {
    __shared__ int rows[MAXNPB * CAP];   // 16.6 KB
    __shared__ int cur[MAXNPB];
    int b = blockIdx.x;
    int nbase = b * NPB;
    int nn = min(NPB, N - nbase);
    if (nn <= 0) return;
    for (int i = threadIdx.x; i < nn; i += 256) cur[i] = 0;
    __syncthreads();
    int s0 = b * SCAP, s1 = s0 + ecnt[b];
    for (int i = s0 + threadIdx.x; i < s1; i += 256) {
        int e  = staging[i];
        int vl = e >> 17;
        int u  = e & 0x1FFFF;
        int p  = atomicAdd(&cur[vl], 1);
        if (p < CAP) rows[vl * CAP + p] = u;
    }
    __syncthreads();
    for (int s = threadIdx.x; s < nn * CAP; s += 256) {
        int node = s / CAP, p = s - node * CAP;
        if (p < min(cur[node], CAP))
            adj[(size_t)(nbase + node) * CAP + p] = rows[s];
    }
    for (int i = threadIdx.x; i < nn; i += 256) {
        int c = cur[i];
        cnt[nbase + i]  = c;
        dinv[nbase + i] = rsqrtf(1.0f + (float)c);
    }
}

// ---------------- weight prep: transpose + f16 convert, [col][k] layout ----------------
__global__ __launch_bounds__(256) void k_wprep(const float* __restrict__ Wi,
                                               const float* __restrict__ W1,
                                               const float* __restrict__ W2,
                                               f16* __restrict__ WiT,
                                               f16* __restrict__ W1T,
                                               f16* __restrict__ W2T) {
    int t = blockIdx.x * 256 + threadIdx.x;
    int stride = gridDim.x * 256;
    for (int i = t; i < DH * DIN; i += stride) {      // WiT[c][k] = Wi[k][c]
        int c = i >> 7, k = i & 127;
        WiT[i] = (f16)Wi[k * DH + c];
    }
    for (int i = t; i < DH * DH; i += stride) {       // W1T/W2T[c][k]
        int c = i >> 6, k = i & 63;
        W1T[i] = (f16)W1[k * DH + c];
        W2T[i] = (f16)W2[k * DH + c];
    }
}

// ---------------- MFMA fused: h0 = relu(x@Wi+bi) (LDS, wave-private); out = f16((h0@W1)*dinv) ----------------
// block = 4 waves x 16 rows = 64-row tile. No __syncthreads (per-wave LDS regions).
__global__ __launch_bounds__(256) void k_lin2(const float* __restrict__ x,
                                              const f16* __restrict__ WiT,
                                              const float* __restrict__ bi,
                                              const f16* __restrict__ W1T,
                                              const float* __restrict__ dinv,
                                              __half* __restrict__ out, int n) {
    __shared__ f16 h0[4 * 16 * 64];   // 8 KB, 2 KB per wave
    int t = threadIdx.x, lane = t & 63, w = t >> 6;
    int rb = blockIdx.x * 64 + w * 16;
    if (rb >= n) return;
    int lr = lane & 15;   // A/D row | B/D col
    int lg = lane >> 4;   // k-group / row-group
    // A-frags: x rows in fragment layout, f32 -> f16
    f16x8 a[4];
    const float* xrow = x + (size_t)(rb + lr) * DIN + lg * 8;
#pragma unroll
    for (int k0 = 0; k0 < 4; k0++) {
        float4 f0 = *(const float4*)(xrow + k0 * 32);
        float4 f1 = *(const float4*)(xrow + k0 * 32 + 4);
        a[k0][0] = (f16)f0.x; a[k0][1] = (f16)f0.y; a[k0][2] = (f16)f0.z; a[k0][3] = (f16)f0.w;
        a[k0][4] = (f16)f1.x; a[k0][5] = (f16)f1.y; a[k0][6] = (f16)f1.z; a[k0][7] = (f16)f1.w;
    }
    char* hwb = (char*)(h0 + w * 16 * 64);
#pragma unroll
    for (int cb = 0; cb < 4; cb++) {
        f32x4 acc = {0.f, 0.f, 0.f, 0.f};
        const f16* wt = WiT + (cb * 16 + lr) * DIN + lg * 8;
#pragma unroll
        for (int k0 = 0; k0 < 4; k0++) {
            f16x8 bf = *(const f16x8*)(wt + k0 * 32);
            acc = __builtin_amdgcn_mfma_f32_16x16x32_f16(a[k0], bf, acc, 0, 0, 0);
        }
        float bv = bi[cb * 16 + lr];
#pragma unroll
        for (int r = 0; r < 4; r++) {
            int row = lg * 4 + r;
            *(f16*)(hwb + swz(row, (cb * 16 + lr) * 2)) = (f16)fmaxf(acc[r] + bv, 0.0f);
        }
    }
    // phase B: A' frags from wave-private LDS (swizzled), B' = W1T
    f16x8 a2[2];
#pragma unroll
    for (int k0 = 0; k0 < 2; k0++)
        a2[k0] = *(const f16x8*)(hwb + swz(lr, k0 * 64 + lg * 16));
    float dv[4];
#pragma unroll
    for (int r = 0; r < 4; r++) dv[r] = dinv[rb + lg * 4 + r];
#pragma unroll
    for (int cb = 0; cb < 4; cb++) {
        f32x4 acc = {0.f, 0.f, 0.f, 0.f};
        const f16* wt = W1T + (cb * 16 + lr) * DH + lg * 8;
        acc = __builtin_amdgcn_mfma_f32_16x16x32_f16(a2[0], *(const f16x8*)(wt), acc, 0, 0, 0);
        acc = __builtin_amdgcn_mfma_f32_16x16x32_f16(a2[1], *(const f16x8*)(wt + 32), acc, 0, 0, 0);
#pragma unroll
        for (int r = 0; r < 4; r++)
            out[(size_t)(rb + lg * 4 + r) * DH + cb * 16 + lr] = __float2half(acc[r] * dv[r]);
    }
}

// ---------------- MFMA 64x64 matmul (f16 in/out, *dinv), no LDS ----------------
__global__ __launch_bounds__(256) void k_mm64(const __half* __restrict__ h,
                                              const f16* __restrict__ WT,
                                              const float* __restrict__ dinv,
                                              __half* __restrict__ out, int n) {
    int t = threadIdx.x, lane = t & 63, w = t >> 6;
    int rb = blockIdx.x * 64 + w * 16;
    if (rb >= n) return;
    int lr = lane & 15, lg = lane >> 4;
    const f16* hp = (const f16*)h + (size_t)(rb + lr) * DH + lg * 8;
    f16x8 a0 = *(const f16x8*)(hp);
    f16x8 a1 = *(const f16x8*)(hp + 32);
    float dv[4];
#pragma unroll
    for (int r = 0; r < 4; r++) dv[r] = dinv[rb + lg * 4 + r];
#pragma unroll
    for (int cb = 0; cb < 4; cb++) {
        const f16* wt = WT + (cb * 16 + lr) * DH + lg * 8;
        f32x4 acc = {0.f, 0.f, 0.f, 0.f};
        acc = __builtin_amdgcn_mfma_f32_16x16x32_f16(a0, *(const f16x8*)(wt), acc, 0, 0, 0);
        acc = __builtin_amdgcn_mfma_f32_16x16x32_f16(a1, *(const f16x8*)(wt + 32), acc, 0, 0, 0);
#pragma unroll
        for (int r = 0; r < 4; r++)
            out[(size_t)(rb + lg * 4 + r) * DH + cb * 16 + lr] = __float2half(acc[r] * dv[r]);
    }
}

// ---------------- gather: shfl-broadcast indices, pk_add_f16 pairing, 32-bit addr ----------------
__global__ __launch_bounds__(256) void k_gather(const int* __restrict__ cnt,
                                                const int* __restrict__ adj,
                                                const __half2* __restrict__ xws,
                                                const float* __restrict__ dinv,
                                                const float* __restrict__ b,
                                                __half* __restrict__ out, int n) {
    int lane = threadIdx.x & 63;
    int v    = blockIdx.x * 4 + (threadIdx.x >> 6);
    if (v >= n) return;
    int half_id = lane >> 5, fp = lane & 31;
    int len = min(cnt[v], CAP);
    const int* row = adj + (size_t)v * CAP;
    int idx = 0;
    if (lane < len) idx = row[lane];
    int len64 = min(len, 64);
    const char* xb = (const char*)xws;
    int fpo = fp << 2;
    float ax = 0.f, ay = 0.f;
    int k = half_id;
    for (; k + 14 < len64; k += 16) {
        int u0 = __shfl(idx, k);
        int u1 = __shfl(idx, k + 2);
        int u2 = __shfl(idx, k + 4);
        int u3 = __shfl(idx, k + 6);
        int u4 = __shfl(idx, k + 8);
        int u5 = __shfl(idx, k + 10);
        int u6 = __shfl(idx, k + 12);
        int u7 = __shfl(idx, k + 14);
        __half2 h0 = *(const __half2*)(xb + ((u0 << 7) | fpo));
        __half2 h1 = *(const __half2*)(xb + ((u1 << 7) | fpo));
        __half2 h2 = *(const __half2*)(xb + ((u2 << 7) | fpo));
        __half2 h3 = *(const __half2*)(xb + ((u3 << 7) | fpo));
        h0 = __hadd2(h0, *(const __half2*)(xb + ((u4 << 7) | fpo)));
        h1 = __hadd2(h1, *(const __half2*)(xb + ((u5 << 7) | fpo)));
        h2 = __hadd2(h2, *(const __half2*)(xb + ((u6 << 7) | fpo)));
        h3 = __hadd2(h3, *(const __half2*)(xb + ((u7 << 7) | fpo)));
        float2 f0 = __half22float2(h0);
        float2 f1 = __half22float2(h1);
        float2 f2 = __half22float2(h2);
        float2 f3 = __half22float2(h3);
        ax += (f0.x + f1.x) + (f2.x + f3.x);
        ay += (f0.y + f1.y) + (f2.y + f3.y);
    }
    for (; k < len64; k += 2) {
        int u0 = __shfl(idx, k);
        float2 f0 = __half22float2(*(const __half2*)(xb + ((u0 << 7) | fpo)));
        ax += f0.x; ay += f0.y;
    }
    for (int j = 64 + half_id; j < len; j += 2) {  // rare tail (deg > 64)
        float2 f0 = __half22float2(xws[(size_t)row[j] * 32 + fp]);
        ax += f0.x; ay += f0.y;
    }
    ax += __shfl_xor(ax, 32);
    ay += __shfl_xor(ay, 32);
    if (half_id == 0) {
        float2 s  = __half22float2(xws[(size_t)v * 32 + fp]);
        float  dv = dinv[v];
        float2 bb = ((const float2*)b)[fp];
        __half2 o = __floats2half2_rn(fmaxf(dv * (ax + s.x) + bb.x, 0.0f),
                                      fmaxf(dv * (ay + s.y) + bb.y, 0.0f));
        ((__half2*)out)[(size_t)v * 32 + fp] = o;
    }
}

// ---------------- pooling (run-length accumulate over sorted batch, f16 in) ----------------
__global__ __launch_bounds__(256) void k_pool(const __half* __restrict__ h,
                                              const int* __restrict__ batch,
                                              float* __restrict__ sums,
                                              int* __restrict__ cnts, int n) {
    int lane = threadIdx.x & 63;
    int w    = blockIdx.x * 4 + (threadIdx.x >> 6);
    int start = w * 64;
    if (start >= n) return;
    int end  = min(start + 64, n);
    int curg = batch[start];
    float acc = 0.f;
    int   c   = 0;
    for (int node = start; node < end; node++) {
        int g = batch[node];
        if (g != curg) {
            atomicAdd(&sums[curg * DH + lane], acc);
            if (lane == 0) atomicAdd(&cnts[curg], c);
            acc = 0.f; c = 0; curg = g;
        }
        acc += __half2float(h[(size_t)node * DH + lane]);
        c++;
    }
    atomicAdd(&sums[curg * DH + lane], acc);
    if (lane == 0) atomicAdd(&cnts[curg], c);
}

// ---------------- head: mean, fc1+relu, fc2, log_softmax ----------------
__global__ __launch_bounds__(64) void k_head(const float* __restrict__ sums,
                                             const int* __restrict__ cnts,
                                             const float* __restrict__ Wf1,
                                             const float* __restrict__ bf1,
                                             const float* __restrict__ Wf2,
                                             const float* __restrict__ bf2,
                                             float* __restrict__ out) {
    int g = blockIdx.x, lane = threadIdx.x;
    float cnt    = (float)max(cnts[g], 1);
    float pooled = sums[g * DH + lane] / cnt;
    float acc = (lane < DFC) ? bf1[lane] : 0.f;
    for (int k = 0; k < DH; k++) {
        float pk = __shfl(pooled, k);
        if (lane < DFC) acc = fmaf(pk, Wf1[k * DFC + lane], acc);
    }
    float gv = fmaxf(acc, 0.f);
    float acc2 = (lane < DC) ? bf2[lane] : 0.f;
    for (int k = 0; k < DFC; k++) {
        float gk = __shfl(gv, k);
        if (lane < DC) acc2 = fmaf(gk, Wf2[k * DC + lane], acc2);
    }
    float v = (lane < DC) ? acc2 : -INFINITY;
    float m = v;
    for (int o = 8; o; o >>= 1) m = fmaxf(m, __shfl_xor(m, o));
    float e = (lane < DC) ? expf(v - m) : 0.f;
    float s = e;
    for (int o = 8; o; o >>= 1) s += __shfl_xor(s, o);
    if (lane < DC) out[g * DC + lane] = v - m - logf(s);
}

extern "C" void kernel_launch(void* const* d_in, const int* in_sizes, int n_in,
                              void* d_out, int out_size, void* d_ws, size_t ws_size,
                              hipStream_t stream) {
    const float* x    = (const float*)d_in[0];
    const int*   ei   = (const int*)d_in[1];
    const int*   batch= (const int*)d_in[2];
    const float* W_in = (const float*)d_in[3];
    const float* b_in = (const float*)d_in[4];
    const float* W1   = (const float*)d_in[5];
    const float* b1   = (const float*)d_in[6];
    const float* W2   = (const float*)d_in[7];
    const float* b2   = (const float*)d_in[8];
    const float* Wf1  = (const float*)d_in[9];
    const float* bf1  = (const float*)d_in[10];
    const float* Wf2  = (const float*)d_in[11];
    const float* bf2  = (const float*)d_in[12];
    float* out = (float*)d_out;

    const int E = in_sizes[1] / 2;      // 1,600,000
    const int N = in_sizes[0] / DIN;    // 100,000
    const int* src = ei;
    const int* dst = ei + E;

    const int NPB = (N + NB - 1) / NB;          // nodes per bucket (49)
    const int NBU = (N + NPB - 1) / NPB;        // buckets used (2041)
    const int EPB = (E + ABLK - 1) / ABLK;      // edges per hist/binplace block

    char* ws = (char*)d_ws;
    size_t off = 0;
    auto alloc = [&](size_t bytes) -> void* {
        void* p = ws + off;
        off = (off + bytes + 255) & ~(size_t)255;
        return p;
    };
    int*    cnt     = (int*)   alloc((size_t)N * 4);
    float*  dinv    = (float*) alloc((size_t)N * 4);
    int*    adj     = (int*)   alloc((size_t)N * CAP * 4);      // 32 MB
    int*    histT   = (int*)   alloc((size_t)ABLK * NB * 4);    // 2 MB
    int*    baseT   = (int*)   alloc((size_t)ABLK * NB * 4);    // 2 MB
    int*    ecnt    = (int*)   alloc((size_t)NB * 4);
    int*    staging = (int*)   alloc((size_t)NB * SCAP * 4);    // 16.8 MB
    __half* hA      = (__half*)alloc((size_t)N * DH * 2);       // 12.8 MB
    __half* hX      = (__half*)alloc((size_t)N * DH * 2);       // 12.8 MB
    float*  sums    = (float*) alloc((size_t)DG * DH * 4);
    int*    cnts    = (int*)   alloc((size_t)DG * 4);
    f16*    WiT     = (f16*)   alloc((size_t)DH * DIN * 2);     // 16 KB
    f16*    W1T     = (f16*)   alloc((size_t)DH * DH * 2);      // 8 KB
    f16*    W2T     = (f16*)   alloc((size_t)DH * DH * 2);      // 8 KB

    // weight prep (transpose + f16)
    k_wprep<<<32, 256, 0, stream>>>(W_in, W1, W2, WiT, W1T, W2T);

    // atomic-free adjacency build: hist(T) -> per-bucket scan(+pool zero) -> binplace -> rows
    k_hist<<<ABLK, 256, 0, stream>>>(src, dst, histT, E, EPB, NPB);
    k_expand<<<NB, 256, 0, stream>>>(histT, baseT, ecnt, sums, cnts);
    k_binplace<<<ABLK, 256, 0, stream>>>(src, dst, baseT, staging, E, EPB, NPB);
    k_rows<<<NBU, 256, 0, stream>>>(staging, ecnt, adj, cnt, dinv, N, NPB);

    // fused MFMA: h0 = relu(xWi+bi); xws1 = f16((h0@W1)*dinv)
    k_lin2<<<(N + 63) / 64, 256, 0, stream>>>(x, WiT, b_in, W1T, dinv, hX, N);

    // conv1 gather + self + bias + relu
    k_gather<<<(N + 3) / 4, 256, 0, stream>>>(cnt, adj, (const __half2*)hX, dinv, b1, hA, N);

    // conv2
    k_mm64<<<(N + 63) / 64, 256, 0, stream>>>(hA, W2T, dinv, hX, N);
    k_gather<<<(N + 3) / 4, 256, 0, stream>>>(cnt, adj, (const __half2*)hX, dinv, b2, hA, N);

    // pooling
    int pw = (N + 63) / 64;
    k_pool<<<(pw + 3) / 4, 256, 0, stream>>>(hA, batch, sums, cnts, N);

    // head
    k_head<<<DG, 64, 0, stream>>>(sums, cnts, Wf1, bf1, Wf2, bf2, out);
}

// Round 12
// 267.007 us; speedup vs baseline: 1.3124x; 1.0857x over previous
//
#include <hip/hip_runtime.h>
#include <hip/hip_fp16.h>
#include <math.h>

// Problem constants (match reference file)
constexpr int DG  = 128;
constexpr int DIN = 128;
constexpr int DH  = 64;
constexpr int DFC = 32;
constexpr int DC  = 10;
constexpr int CAP  = 80;    // adjacency capacity/node (deg ~ Poisson(32); P(>80)~1e-13)
constexpr int NPB  = 64;    // nodes per bucket (power of 2 -> shift addressing)
constexpr int NB   = 1563;  // ceil(100000/64) buckets
constexpr int ABLK = 256;   // edge-chunk blocks (hist/binplace use identical partition)
constexpr int SCAP = 2560;  // staging capacity per bucket (avg fill ~2048, +11 sigma)

typedef _Float16 f16;
typedef f16  f16x8 __attribute__((ext_vector_type(8)));
typedef float f32x4 __attribute__((ext_vector_type(4)));

// XOR-swizzled byte offset within a 128-B LDS row (bank-conflict-free frag reads)
__device__ __forceinline__ int swz(int row, int byte_in_row) {
    return row * 128 + (byte_in_row ^ ((row & 7) << 4));
}

// ---------------- build 1: per-block LDS histogram, bucket-major output ----------------
__global__ __launch_bounds__(256) void k_hist(const int* __restrict__ src,
                                              const int* __restrict__ dst,
                                              int* __restrict__ histT,   // [NB][ABLK]
                                              int E, int EPB) {
    __shared__ int h[NB];
    for (int i = threadIdx.x; i < NB; i += 256) h[i] = 0;
    __syncthreads();
    int e0 = blockIdx.x * EPB, e1 = min(e0 + EPB, E);
    for (int i = e0 + threadIdx.x; i < e1; i += 256) {
        int u = src[i], v = dst[i];
        atomicAdd(&h[v >> 6], 1);
        atomicAdd(&h[u >> 6], 1);
    }
    __syncthreads();
    for (int i = threadIdx.x; i < NB; i += 256)
        histT[(size_t)i * ABLK + blockIdx.x] = h[i];
}

// ---------------- build 2: per-bucket LDS scan -> bases + totals (+pool zero) ----------------
__global__ __launch_bounds__(256) void k_expand(const int* __restrict__ histT,
                                                int* __restrict__ baseT,   // [NB][ABLK]
                                                int* __restrict__ ecnt,
                                                float* __restrict__ sums,
                                                int* __restrict__ cnts) {
    __shared__ int s[256];
    int b = blockIdx.x, t = threadIdx.x;
    int v = histT[(size_t)b * ABLK + t];
    s[t] = v;
    __syncthreads();
    for (int o = 1; o < 256; o <<= 1) {
        int tv = (t >= o) ? s[t - o] : 0;
        __syncthreads();
        s[t] += tv;
        __syncthreads();
    }
    int incl = s[t];
    baseT[(size_t)b * ABLK + t] = b * SCAP + incl - v;   // exclusive + bucket offset
    if (t == 255) ecnt[b] = min(incl, SCAP);
    int gid = b * 256 + t;
    if (gid < DG * DH) sums[gid] = 0.0f;
    if (gid < DG) cnts[gid] = 0;
}

// ---------------- build 3: place packed entries into bucket-grouped staging ----------------
__global__ __launch_bounds__(256) void k_binplace(const int* __restrict__ src,
                                                  const int* __restrict__ dst,
                                                  const int* __restrict__ baseT,
                                                  int* __restrict__ staging,
                                                  int E, int EPB) {
    __shared__ int lcnt[NB];
    __shared__ int lbase[NB];
    int blk = blockIdx.x;
    for (int i = threadIdx.x; i < NB; i += 256) {
        lcnt[i]  = 0;
        lbase[i] = baseT[(size_t)i * ABLK + blk];
    }
    __syncthreads();
    int e0 = blk * EPB, e1 = min(e0 + EPB, E);
    for (int i = e0 + threadIdx.x; i < e1; i += 256) {
        int u = src[i], v = dst[i];
        int bv = v >> 6, bu = u >> 6;
        int rv = atomicAdd(&lcnt[bv], 1);
        int sv = lbase[bv] + rv;
        if (sv < (bv + 1) * SCAP) staging[sv] = ((v & 63) << 17) | u;
        int ru = atomicAdd(&lcnt[bu], 1);
        int su = lbase[bu] + ru;
        if (su < (bu + 1) * SCAP) staging[su] = ((u & 63) << 17) | v;
    }
}

// ---------------- build 4: one block per bucket -> adj rows + cnt + dinv ----------------
__global__ __launch_bounds__(256) void k_rows(const int* __restrict__ staging,
                                              const int* __restrict__ ecnt,
                                              int* __restrict__ adj,
                                              int* __restrict__ cnt,
                                              float* __restrict__ dinv,
                                              int N) {
    __shared__ int rows[NPB * CAP];   // 20.5 KB
    __shared__ int cur[NPB];
    int b = blockIdx.x;
    int nbase = b * NPB;
    int nn = min(NPB, N - nbase);
    if (nn <= 0) return;
    for (int i = threadIdx.x; i < nn; i += 256) cur[i] = 0;
    __syncthreads();
    int s0 = b * SCAP, s1 = s0 + ecnt[b];
    for (int i = s0 + threadIdx.x; i < s1; i += 256) {
        int e  = staging[i];
        int vl = e >> 17;
        int u  = e & 0x1FFFF;
        int p  = atomicAdd(&cur[vl], 1);
        if (p < CAP) rows[vl * CAP + p] = u;
    }
    __syncthreads();
    for (int s = threadIdx.x; s < nn * CAP; s += 256) {
        int node = s / CAP, p = s - node * CAP;
        if (p < min(cur[node], CAP))
            adj[(size_t)(nbase + node) * CAP + p] = rows[s];
    }
    for (int i = threadIdx.x; i < nn; i += 256) {
        int c = cur[i];
        cnt[nbase + i]  = c;
        dinv[nbase + i] = rsqrtf(1.0f + (float)c);
    }
}

// ---------------- weight prep: transpose + f16 convert, [col][k] layout ----------------
__global__ __launch_bounds__(256) void k_wprep(const float* __restrict__ Wi,
                                               const float* __restrict__ W1,
                                               const float* __restrict__ W2,
                                               f16* __restrict__ WiT,
                                               f16* __restrict__ W1T,
                                               f16* __restrict__ W2T) {
    int t = blockIdx.x * 256 + threadIdx.x;
    int stride = gridDim.x * 256;
    for (int i = t; i < DH * DIN; i += stride) {      // WiT[c][k] = Wi[k][c]
        int c = i >> 7, k = i & 127;
        WiT[i] = (f16)Wi[k * DH + c];
    }
    for (int i = t; i < DH * DH; i += stride) {       // W1T/W2T[c][k]
        int c = i >> 6, k = i & 63;
        W1T[i] = (f16)W1[k * DH + c];
        W2T[i] = (f16)W2[k * DH + c];
    }
}

// ---------------- MFMA fused: h0 = relu(x@Wi+bi) (LDS, wave-private); out = f16((h0@W1)*dinv) ----------------
__global__ __launch_bounds__(256) void k_lin2(const float* __restrict__ x,
                                              const f16* __restrict__ WiT,
                                              const float* __restrict__ bi,
                                              const f16* __restrict__ W1T,
                                              const float* __restrict__ dinv,
                                              __half* __restrict__ out, int n) {
    __shared__ f16 h0[4 * 16 * 64];   // 8 KB, 2 KB per wave
    int t = threadIdx.x, lane = t & 63, w = t >> 6;
    int rb = blockIdx.x * 64 + w * 16;
    if (rb >= n) return;
    int lr = lane & 15;   // A/D row | B/D col
    int lg = lane >> 4;   // k-group / row-group
    f16x8 a[4];
    const float* xrow = x + (size_t)(rb + lr) * DIN + lg * 8;
#pragma unroll
    for (int k0 = 0; k0 < 4; k0++) {
        float4 f0 = *(const float4*)(xrow + k0 * 32);
        float4 f1 = *(const float4*)(xrow + k0 * 32 + 4);
        a[k0][0] = (f16)f0.x; a[k0][1] = (f16)f0.y; a[k0][2] = (f16)f0.z; a[k0][3] = (f16)f0.w;
        a[k0][4] = (f16)f1.x; a[k0][5] = (f16)f1.y; a[k0][6] = (f16)f1.z; a[k0][7] = (f16)f1.w;
    }
    char* hwb = (char*)(h0 + w * 16 * 64);
#pragma unroll
    for (int cb = 0; cb < 4; cb++) {
        f32x4 acc = {0.f, 0.f, 0.f, 0.f};
        const f16* wt = WiT + (cb * 16 + lr) * DIN + lg * 8;
#pragma unroll
        for (int k0 = 0; k0 < 4; k0++) {
            f16x8 bf = *(const f16x8*)(wt + k0 * 32);
            acc = __builtin_amdgcn_mfma_f32_16x16x32_f16(a[k0], bf, acc, 0, 0, 0);
        }
        float bv = bi[cb * 16 + lr];
#pragma unroll
        for (int r = 0; r < 4; r++) {
            int row = lg * 4 + r;
            *(f16*)(hwb + swz(row, (cb * 16 + lr) * 2)) = (f16)fmaxf(acc[r] + bv, 0.0f);
        }
    }
    f16x8 a2[2];
#pragma unroll
    for (int k0 = 0; k0 < 2; k0++)
        a2[k0] = *(const f16x8*)(hwb + swz(lr, k0 * 64 + lg * 16));
    float dv[4];
#pragma unroll
    for (int r = 0; r < 4; r++) dv[r] = dinv[rb + lg * 4 + r];
#pragma unroll
    for (int cb = 0; cb < 4; cb++) {
        f32x4 acc = {0.f, 0.f, 0.f, 0.f};
        const f16* wt = W1T + (cb * 16 + lr) * DH + lg * 8;
        acc = __builtin_amdgcn_mfma_f32_16x16x32_f16(a2[0], *(const f16x8*)(wt), acc, 0, 0, 0);
        acc = __builtin_amdgcn_mfma_f32_16x16x32_f16(a2[1], *(const f16x8*)(wt + 32), acc, 0, 0, 0);
#pragma unroll
        for (int r = 0; r < 4; r++)
            out[(size_t)(rb + lg * 4 + r) * DH + cb * 16 + lr] = __float2half(acc[r] * dv[r]);
    }
}

// ---------------- gather inner: returns (ax,ay) combined into half 0 ----------------
__device__ __forceinline__ void gather_node(int v, const int* __restrict__ cnt,
                                            const int* __restrict__ adj,
                                            const char* __restrict__ xb,
                                            int lane, int half_id, int fpo,
                                            float& ax, float& ay) {
    int len = min(cnt[v], CAP);
    const int* row = adj + (size_t)v * CAP;
    int idx = 0;
    if (lane < len) idx = row[lane];
    int len64 = min(len, 64);
    ax = 0.f; ay = 0.f;
    int k = half_id;
    for (; k + 14 < len64; k += 16) {
        int u0 = __shfl(idx, k);
        int u1 = __shfl(idx, k + 2);
        int u2 = __shfl(idx, k + 4);
        int u3 = __shfl(idx, k + 6);
        int u4 = __shfl(idx, k + 8);
        int u5 = __shfl(idx, k + 10);
        int u6 = __shfl(idx, k + 12);
        int u7 = __shfl(idx, k + 14);
        __half2 h0 = *(const __half2*)(xb + ((u0 << 7) | fpo));
        __half2 h1 = *(const __half2*)(xb + ((u1 << 7) | fpo));
        __half2 h2 = *(const __half2*)(xb + ((u2 << 7) | fpo));
        __half2 h3 = *(const __half2*)(xb + ((u3 << 7) | fpo));
        h0 = __hadd2(h0, *(const __half2*)(xb + ((u4 << 7) | fpo)));
        h1 = __hadd2(h1, *(const __half2*)(xb + ((u5 << 7) | fpo)));
        h2 = __hadd2(h2, *(const __half2*)(xb + ((u6 << 7) | fpo)));
        h3 = __hadd2(h3, *(const __half2*)(xb + ((u7 << 7) | fpo)));
        float2 f0 = __half22float2(h0);
        float2 f1 = __half22float2(h1);
        float2 f2 = __half22float2(h2);
        float2 f3 = __half22float2(h3);
        ax += (f0.x + f1.x) + (f2.x + f3.x);
        ay += (f0.y + f1.y) + (f2.y + f3.y);
    }
    for (; k < len64; k += 2) {
        int u0 = __shfl(idx, k);
        float2 f0 = __half22float2(*(const __half2*)(xb + ((u0 << 7) | fpo)));
        ax += f0.x; ay += f0.y;
    }
    for (int j = 64 + half_id; j < len; j += 2) {  // rare tail (deg > 64)
        float2 f0 = __half22float2(*(const __half2*)(xb + ((row[j] << 7) | fpo)));
        ax += f0.x; ay += f0.y;
    }
    ax += __shfl_xor(ax, 32);
    ay += __shfl_xor(ay, 32);
}

// ---------------- fused gather1 + conv2 matmul ----------------
// wave = 16 nodes: gather each into wave-private LDS f16 tile, then MFMA (h@W2T)*dinv
__global__ __launch_bounds__(256) void k_g1(const int* __restrict__ cnt,
                                            const int* __restrict__ adj,
                                            const __half2* __restrict__ xws,
                                            const float* __restrict__ dinv,
                                            const float* __restrict__ b,
                                            const f16* __restrict__ W2T,
                                            __half* __restrict__ out, int n) {
    __shared__ char ht[4 * 2048];   // 8 KB, 2 KB per wave
    int t = threadIdx.x, lane = t & 63, w = t >> 6;
    int rb = blockIdx.x * 64 + w * 16;
    if (rb >= n) return;
    int half_id = lane >> 5, fp = lane & 31, fpo = fp << 2;
    const char* xb = (const char*)xws;
    char* wb = ht + w * 2048;
#pragma unroll 1
    for (int i = 0; i < 16; i++) {
        int v = rb + i;
        float ax, ay;
        gather_node(v, cnt, adj, xb, lane, half_id, fpo, ax, ay);
        if (half_id == 0) {
            float2 s  = __half22float2(*(const __half2*)(xb + ((v << 7) | fpo)));
            float  dv = dinv[v];
            float2 bb = ((const float2*)b)[fp];
            __half2 hh = __floats2half2_rn(fmaxf(dv * (ax + s.x) + bb.x, 0.0f),
                                           fmaxf(dv * (ay + s.y) + bb.y, 0.0f));
            *(__half2*)(wb + swz(i, fpo)) = hh;
        }
    }
    // MFMA phase (wave-private tile; compiler inserts lgkmcnt waits)
    int lr = lane & 15, lg = lane >> 4;
    f16x8 a0 = *(const f16x8*)(wb + swz(lr, lg * 16));
    f16x8 a1 = *(const f16x8*)(wb + swz(lr, 64 + lg * 16));
    float dvr[4];
#pragma unroll
    for (int r = 0; r < 4; r++) dvr[r] = dinv[rb + lg * 4 + r];
#pragma unroll
    for (int cb = 0; cb < 4; cb++) {
        const f16* wt = W2T + (cb * 16 + lr) * DH + lg * 8;
        f32x4 acc = {0.f, 0.f, 0.f, 0.f};
        acc = __builtin_amdgcn_mfma_f32_16x16x32_f16(a0, *(const f16x8*)(wt), acc, 0, 0, 0);
        acc = __builtin_amdgcn_mfma_f32_16x16x32_f16(a1, *(const f16x8*)(wt + 32), acc, 0, 0, 0);
#pragma unroll
        for (int r = 0; r < 4; r++)
            out[(size_t)(rb + lg * 4 + r) * DH + cb * 16 + lr] = __float2half(acc[r] * dvr[r]);
    }
}

// ---------------- fused gather2 + pooling (run-length over sorted batch) ----------------
__global__ __launch_bounds__(256) void k_g2(const int* __restrict__ cnt,
                                            const int* __restrict__ adj,
                                            const __half2* __restrict__ xws,
                                            const float* __restrict__ dinv,
                                            const float* __restrict__ b,
                                            const int* __restrict__ batch,
                                            float* __restrict__ sums,
                                            int* __restrict__ cnts, int n) {
    int t = threadIdx.x, lane = t & 63, w = t >> 6;
    int rb = blockIdx.x * 64 + w * 16;
    if (rb >= n) return;
    int half_id = lane >> 5, fp = lane & 31, fpo = fp << 2;
    const char* xb = (const char*)xws;
    int curg = -1, c = 0;
    float pax = 0.f, pay = 0.f;
#pragma unroll 1
    for (int i = 0; i < 16; i++) {
        int v = rb + i;
        float ax, ay;
        gather_node(v, cnt, adj, xb, lane, half_id, fpo, ax, ay);
        float2 s  = __half22float2(*(const __half2*)(xb + ((v << 7) | fpo)));
        float  dv = dinv[v];
        float2 bb = ((const float2*)b)[fp];
        float ox = fmaxf(dv * (ax + s.x) + bb.x, 0.0f);
        float oy = fmaxf(dv * (ay + s.y) + bb.y, 0.0f);
        int g = batch[v];
        if (g != curg) {
            if (curg >= 0 && half_id == 0) {
                atomicAdd(&sums[curg * DH + 2 * fp],     pax);
                atomicAdd(&sums[curg * DH + 2 * fp + 1], pay);
                if (lane == 0) atomicAdd(&cnts[curg], c);
            }
            curg = g; pax = 0.f; pay = 0.f; c = 0;
        }
        if (half_id == 0) { pax += ox; pay += oy; }
        c++;
    }
    if (curg >= 0 && half_id == 0) {
        atomicAdd(&sums[curg * DH + 2 * fp],     pax);
        atomicAdd(&sums[curg * DH + 2 * fp + 1], pay);
        if (lane == 0) atomicAdd(&cnts[curg], c);
    }
}

// ---------------- head: mean, fc1+relu, fc2, log_softmax ----------------
__global__ __launch_bounds__(64) void k_head(const float* __restrict__ sums,
                                             const int* __restrict__ cnts,
                                             const float* __restrict__ Wf1,
                                             const float* __restrict__ bf1,
                                             const float* __restrict__ Wf2,
                                             const float* __restrict__ bf2,
                                             float* __restrict__ out) {
    int g = blockIdx.x, lane = threadIdx.x;
    float cnt    = (float)max(cnts[g], 1);
    float pooled = sums[g * DH + lane] / cnt;
    float acc = (lane < DFC) ? bf1[lane] : 0.f;
    for (int k = 0; k < DH; k++) {
        float pk = __shfl(pooled, k);
        if (lane < DFC) acc = fmaf(pk, Wf1[k * DFC + lane], acc);
    }
    float gv = fmaxf(acc, 0.f);
    float acc2 = (lane < DC) ? bf2[lane] : 0.f;
    for (int k = 0; k < DFC; k++) {
        float gk = __shfl(gv, k);
        if (lane < DC) acc2 = fmaf(gk, Wf2[k * DC + lane], acc2);
    }
    float v = (lane < DC) ? acc2 : -INFINITY;
    float m = v;
    for (int o = 8; o; o >>= 1) m = fmaxf(m, __shfl_xor(m, o));
    float e = (lane < DC) ? expf(v - m) : 0.f;
    float s = e;
    for (int o = 8; o; o >>= 1) s += __shfl_xor(s, o);
    if (lane < DC) out[g * DC + lane] = v - m - logf(s);
}

extern "C" void kernel_launch(void* const* d_in, const int* in_sizes, int n_in,
                              void* d_out, int out_size, void* d_ws, size_t ws_size,
                              hipStream_t stream) {
    const float* x    = (const float*)d_in[0];
    const int*   ei   = (const int*)d_in[1];
    const int*   batch= (const int*)d_in[2];
    const float* W_in = (const float*)d_in[3];
    const float* b_in = (const float*)d_in[4];
    const float* W1   = (const float*)d_in[5];
    const float* b1   = (const float*)d_in[6];
    const float* W2   = (const float*)d_in[7];
    const float* b2   = (const float*)d_in[8];
    const float* Wf1  = (const float*)d_in[9];
    const float* bf1  = (const float*)d_in[10];
    const float* Wf2  = (const float*)d_in[11];
    const float* bf2  = (const float*)d_in[12];
    float* out = (float*)d_out;

    const int E = in_sizes[1] / 2;      // 1,600,000
    const int N = in_sizes[0] / DIN;    // 100,000
    const int* src = ei;
    const int* dst = ei + E;

    const int NBU = (N + NPB - 1) / NPB;        // buckets used (1563)
    const int EPB = (E + ABLK - 1) / ABLK;      // edges per hist/binplace block

    char* ws = (char*)d_ws;
    size_t off = 0;
    auto alloc = [&](size_t bytes) -> void* {
        void* p = ws + off;
        off = (off + bytes + 255) & ~(size_t)255;
        return p;
    };
    int*    cnt     = (int*)   alloc((size_t)N * 4);
    float*  dinv    = (float*) alloc((size_t)N * 4);
    int*    adj     = (int*)   alloc((size_t)N * CAP * 4);      // 32 MB
    int*    histT   = (int*)   alloc((size_t)NB * ABLK * 4);    // 1.6 MB
    int*    baseT   = (int*)   alloc((size_t)NB * ABLK * 4);    // 1.6 MB
    int*    ecnt    = (int*)   alloc((size_t)NB * 4);
    int*    staging = (int*)   alloc((size_t)NB * SCAP * 4);    // 16 MB
    __half* hA      = (__half*)alloc((size_t)N * DH * 2);       // 12.8 MB (xws2)
    __half* hX      = (__half*)alloc((size_t)N * DH * 2);       // 12.8 MB (xws1)
    float*  sums    = (float*) alloc((size_t)DG * DH * 4);
    int*    cnts    = (int*)   alloc((size_t)DG * 4);
    f16*    WiT     = (f16*)   alloc((size_t)DH * DIN * 2);
    f16*    W1T     = (f16*)   alloc((size_t)DH * DH * 2);
    f16*    W2T     = (f16*)   alloc((size_t)DH * DH * 2);

    // weight prep (transpose + f16)
    k_wprep<<<32, 256, 0, stream>>>(W_in, W1, W2, WiT, W1T, W2T);

    // atomic-free adjacency build: hist(T) -> per-bucket scan(+pool zero) -> binplace -> rows
    k_hist<<<ABLK, 256, 0, stream>>>(src, dst, histT, E, EPB);
    k_expand<<<NB, 256, 0, stream>>>(histT, baseT, ecnt, sums, cnts);
    k_binplace<<<ABLK, 256, 0, stream>>>(src, dst, baseT, staging, E, EPB);
    k_rows<<<NBU, 256, 0, stream>>>(staging, ecnt, adj, cnt, dinv, N);

    // fused MFMA: h0 = relu(xWi+bi); xws1 = f16((h0@W1)*dinv)
    k_lin2<<<(N + 63) / 64, 256, 0, stream>>>(x, WiT, b_in, W1T, dinv, hX, N);

    // fused gather1 + conv2 matmul: xws2 = f16((relu(gather1)+b1 stuff @ W2T)*dinv)
    k_g1<<<(N + 63) / 64, 256, 0, stream>>>(cnt, adj, (const __half2*)hX, dinv, b1, W2T, hA, N);

    // fused gather2 + pooling
    k_g2<<<(N + 63) / 64, 256, 0, stream>>>(cnt, adj, (const __half2*)hA, dinv, b2, batch, sums, cnts, N);

    // head
    k_head<<<DG, 64, 0, stream>>>(sums, cnts, Wf1, bf1, Wf2, bf2, out);
}